// Round 1
// baseline (4422.215 us; speedup 1.0000x reference)
//
#include <hip/hip_runtime.h>
#include <math.h>

#define COMMITMENT_COST 0.25f
#define DECAY 0.99f
#define EPSILON 1e-05f
#define KCODES 1024
#define DIM 256
#define NTOK 32768

// out-buffer float offsets (concatenated return tuple)
#define O_QUANT 0
#define O_LOSS  8388608
#define O_IDX   8388609
#define O_CS    8421377
#define O_EMAW  8422401
#define O_EMB   8684545

// scratch in the new_embedding slot (262144 floats, written LAST by fin).
// O_EMB is odd -> +1 float makes packed u64 8-byte aligned.
#define SE_PACKED 1        // u64 x 32768 -> floats [1, 65537)
#define SE_ESQ    65544
#define SE_ZSQ    66568    // 32768 floats
#define SE_HIST   99336    // 1024 ints

// scratch in the O_QUANT slot (8388608 floats, written by mid AFTER recheck).
// All consumers (dist_mfma, recheck) run before mid.
#define SQ_ZH    0         // ushort[32768*256] -> floats [0, 4194304)
#define SQ_EH    4194304   // ushort[1024*256]  -> floats [4194304, 4325376)
#define SQ_MG    4325376   // u64[32768]        -> floats [4325376, 4390912)
#define SQ_CC    4390912   // int[32768]        -> floats [4390912, 4423680)
#define SQ_CAND  4423680   // u64[32768*28]     -> floats [4423680, 6258688)

// exact-argmin recovery: candidate window threshold.
// Bound: 2*eta_ref (3.8e-5) + 2*eps_bf16 (1.6e-3) ~= 3.3e-3; theta = 3.7x margin.
#define THETA 0.012f
#define CAND_CAP 28

typedef __attribute__((ext_vector_type(8))) short bf16x8;
typedef __attribute__((ext_vector_type(4))) float f32x4;

__device__ __forceinline__ unsigned short f2bf(float x) {
    unsigned u = __float_as_uint(x);
    return (unsigned short)((u + 0x7FFFu + ((u >> 16) & 1u)) >> 16);  // RNE
}
__device__ __forceinline__ unsigned mono(float f) {   // order-preserving f32->u32
    unsigned u = __float_as_uint(f);
    return u ^ ((u & 0x80000000u) ? 0xFFFFFFFFu : 0x80000000u);
}
__device__ __forceinline__ float invmono(unsigned m) {
    unsigned u = m ^ ((m & 0x80000000u) ? 0x80000000u : 0xFFFFFFFFu);
    return __uint_as_float(u);
}

// ------- pre: zsq/esq, bf16 casts zh/eh, zero dw/hist/loss, init packed/Mg/cc -------
__global__ void pre_kernel(const float* __restrict__ z, const float* __restrict__ E,
                           float* __restrict__ zsq, float* __restrict__ esq,
                           float* __restrict__ dw, int* __restrict__ hist,
                           unsigned long long* __restrict__ packed,
                           float* __restrict__ loss,
                           unsigned short* __restrict__ zh,
                           unsigned short* __restrict__ eh,
                           unsigned long long* __restrict__ Mg,
                           int* __restrict__ ccount) {
    const int b = blockIdx.x;
    const int wave = threadIdx.x >> 6;
    const int lane = threadIdx.x & 63;
    if (b < NTOK / 4) {
        int token = b * 4 + wave;
        float4 v = ((const float4*)(z + (size_t)token * DIM))[lane];
        ushort4 h;
        h.x = f2bf(v.x); h.y = f2bf(v.y); h.z = f2bf(v.z); h.w = f2bf(v.w);
        *(ushort4*)(zh + (size_t)token * DIM + lane * 4) = h;
        float s = v.x * v.x + v.y * v.y + v.z * v.z + v.w * v.w;
        #pragma unroll
        for (int off = 32; off > 0; off >>= 1) s += __shfl_down(s, off);
        if (lane == 0) zsq[token] = s;
        if (threadIdx.x < 4) {
            packed[b * 4 + threadIdx.x] = ~0ull;
            Mg[b * 4 + threadIdx.x] = ~0ull;
            ccount[b * 4 + threadIdx.x] = 0;
        }
        if (b == 0 && threadIdx.x == 4) loss[0] = 0.0f;
    } else {
        int eb = b - NTOK / 4;                 // 0..255
        int k = eb * 4 + wave;
        float4 v = ((const float4*)(E + (size_t)k * DIM))[lane];
        ushort4 h;
        h.x = f2bf(v.x); h.y = f2bf(v.y); h.z = f2bf(v.z); h.w = f2bf(v.w);
        *(ushort4*)(eh + (size_t)k * DIM + lane * 4) = h;
        float s = v.x * v.x + v.y * v.y + v.z * v.z + v.w * v.w;
        #pragma unroll
        for (int off = 32; off > 0; off >>= 1) s += __shfl_down(s, off);
        if (lane == 0) esq[k] = s;
        float4 zero4 = {0.f, 0.f, 0.f, 0.f};
        ((float4*)dw)[eb * 256 + threadIdx.x] = zero4;
        if (threadIdx.x < 4) hist[eb * 4 + threadIdx.x] = 0;
    }
}

// ---------------- bf16 MFMA approximate-distance pass ----------------
// delta~(t,j) = esq[j] - 2 * (zh . eh)  via mfma_f32_16x16x32_bf16.
// Tile 128 tok x 128 codes, BK=32, 4 waves (2x2), 4x4 16x16 frags/wave.
// LDS rows padded to 40 ushort (80 B) -> conflict-free b128 frag reads.
// Emits: per-token global approx-min (Mg, mono-encoded atomicMin) and
// all (token,code,delta~) with delta~ <= block-row-min + THETA into cand[].
// Guarantee: the reference argmin is always within THETA of the block-local
// min of its own tile (error-bound arithmetic in header comment).
__global__ __launch_bounds__(256) void dist_mfma_kernel(
        const unsigned short* __restrict__ zh, const unsigned short* __restrict__ eh,
        const float* __restrict__ esq,
        unsigned long long* __restrict__ Mg, int* __restrict__ ccount,
        unsigned long long* __restrict__ cand) {
    __shared__ unsigned short Als[128 * 40];
    __shared__ unsigned short Bls[128 * 40];
    __shared__ unsigned long long scr[128][2];

    const int tid = threadIdx.x;
    const int wid = tid >> 6;
    const int lane = tid & 63;
    const int wm = wid >> 1, wn = wid & 1;
    const int l15 = lane & 15, l4 = lane >> 4;
    const int tok0 = (blockIdx.x >> 3) * 128;
    const int c0 = (blockIdx.x & 7) * 128;

    // staging: thread covers rows srow, srow+64 at element col gc8..gc8+7
    const int srow = tid >> 2;              // 0..63
    const int gc8 = (tid & 3) * 8;
    const unsigned short* zsrc = zh + (size_t)(tok0 + srow) * 256 + gc8;
    const unsigned short* esrc = eh + (size_t)(c0 + srow) * 256 + gc8;
    unsigned short* adst = Als + srow * 40 + gc8;
    unsigned short* bdst = Bls + srow * 40 + gc8;

    f32x4 acc[4][4];
    #pragma unroll
    for (int i = 0; i < 4; ++i)
        #pragma unroll
        for (int j = 0; j < 4; ++j)
            acc[i][j] = (f32x4){0.f, 0.f, 0.f, 0.f};

    for (int kt = 0; kt < 8; ++kt) {
        const int kk = kt * 32;
        // issue global loads BEFORE the barrier: latency hides under the wait
        bf16x8 a0 = *(const bf16x8*)(zsrc + kk);
        bf16x8 a1 = *(const bf16x8*)(zsrc + 64 * 256 + kk);
        bf16x8 b0 = *(const bf16x8*)(esrc + kk);
        bf16x8 b1 = *(const bf16x8*)(esrc + 64 * 256 + kk);
        __syncthreads();                    // previous iter's frag reads done
        *(bf16x8*)adst = a0;
        *(bf16x8*)(adst + 64 * 40) = a1;
        *(bf16x8*)bdst = b0;
        *(bf16x8*)(bdst + 64 * 40) = b1;
        __syncthreads();
        // fragments: A row = lane&15, k = (lane>>4)*8 + i (contiguous 8 bf16);
        // B symmetric (col = lane&15). C/D: col=lane&15, row=(lane>>4)*4+reg.
        bf16x8 av[4], bv[4];
        #pragma unroll
        for (int f = 0; f < 4; ++f) {
            av[f] = *(const bf16x8*)(Als + (wm * 64 + f * 16 + l15) * 40 + l4 * 8);
            bv[f] = *(const bf16x8*)(Bls + (wn * 64 + f * 16 + l15) * 40 + l4 * 8);
        }
        #pragma unroll
        for (int i = 0; i < 4; ++i)
            #pragma unroll
            for (int j = 0; j < 4; ++j)
                acc[i][j] = __builtin_amdgcn_mfma_f32_16x16x32_bf16(
                    av[i], bv[j], acc[i][j], 0, 0, 0);
    }

    // epilogue: delta~ = sq[j] - 2*acc; per-row block-local min; window emit
    float sq[4];
    #pragma unroll
    for (int j = 0; j < 4; ++j) sq[j] = esq[c0 + wn * 64 + j * 16 + l15];

    #pragma unroll
    for (int i = 0; i < 4; ++i) {
        #pragma unroll
        for (int r = 0; r < 4; ++r) {
            float v = 3.4e38f;
            #pragma unroll
            for (int j = 0; j < 4; ++j)
                v = fminf(v, sq[j] - 2.0f * acc[i][j][r]);
            #pragma unroll
            for (int m = 1; m < 16; m <<= 1)
                v = fminf(v, __shfl_xor(v, m));
            if (l15 == 0)
                scr[wm * 64 + i * 16 + l4 * 4 + r][wn] =
                    ((unsigned long long)mono(v)) << 32;
        }
    }
    __syncthreads();
    if (tid < 128) {
        unsigned long long a = scr[tid][0], b = scr[tid][1];
        unsigned long long mn = a < b ? a : b;
        scr[tid][0] = mn;
        atomicMin(&Mg[tok0 + tid], mn);
    }
    __syncthreads();
    #pragma unroll
    for (int i = 0; i < 4; ++i) {
        #pragma unroll
        for (int r = 0; r < 4; ++r) {
            const int rowl = wm * 64 + i * 16 + l4 * 4 + r;
            const float thr = invmono((unsigned)(scr[rowl][0] >> 32)) + THETA;
            #pragma unroll
            for (int j = 0; j < 4; ++j) {
                float d = sq[j] - 2.0f * acc[i][j][r];
                if (d <= thr) {
                    int token = tok0 + rowl;
                    int slot = atomicAdd(&ccount[token], 1);
                    if (slot < CAND_CAP)
                        cand[(size_t)token * CAND_CAP + slot] =
                            (((unsigned long long)__float_as_uint(d)) << 32) |
                            (unsigned)(c0 + wn * 64 + j * 16 + l15);
                }
            }
        }
    }
}

// ------- recheck: exact fp32 dv for filtered candidates, ref-order ----------
// dv = fl(fl(An + sq) - 2*acc), acc = seq fmaf over d ascending (x,y,z,w) —
// bit-identical to the previously-passing fp32 kernel's epilogue. Packed
// (dv_bits<<32)|idx u64 atomicMin reproduces first-index tie-break.
// Overflow (ccount > CAND_CAP, ~never): full exact 1024-code scan fallback.
__global__ __launch_bounds__(256) void recheck_kernel(
        const float* __restrict__ z, const float* __restrict__ E,
        const float* __restrict__ zsq, const float* __restrict__ esq,
        const unsigned long long* __restrict__ Mg, const int* __restrict__ ccount,
        const unsigned long long* __restrict__ cand,
        unsigned long long* __restrict__ packed) {
    const int wave = threadIdx.x >> 6, lane = threadIdx.x & 63;
    const int token = blockIdx.x * 4 + wave;
    const int cnt = ccount[token];
    const float Mt = invmono((unsigned)(Mg[token] >> 32));
    const float An = zsq[token];
    const float4* zp = (const float4*)(z + (size_t)token * 256);

    if (cnt <= CAND_CAP) {
        if (lane < cnt) {
            unsigned long long e = cand[(size_t)token * CAND_CAP + lane];
            float dt = __uint_as_float((unsigned)(e >> 32));
            int code = (int)(unsigned)(e & 0xFFFFFFFFull);
            if (dt <= Mt + THETA) {
                const float4* ep = (const float4*)(E + (size_t)code * 256);
                float acc = 0.0f;
                #pragma unroll 8
                for (int q = 0; q < 64; ++q) {
                    float4 a = zp[q], b = ep[q];
                    acc = fmaf(a.x, b.x, acc); acc = fmaf(a.y, b.y, acc);
                    acc = fmaf(a.z, b.z, acc); acc = fmaf(a.w, b.w, acc);
                }
                float S = An + esq[code];
                float dv = S - 2.0f * acc;
                atomicMin(&packed[token],
                    (((unsigned long long)__float_as_uint(dv)) << 32) | (unsigned)code);
            }
        }
    } else {
        float best = 3.4e38f; int bid = 0x7fffffff;
        for (int code = lane; code < KCODES; code += 64) {
            const float4* ep = (const float4*)(E + (size_t)code * 256);
            float acc = 0.0f;
            for (int q = 0; q < 64; ++q) {
                float4 a = zp[q], b = ep[q];
                acc = fmaf(a.x, b.x, acc); acc = fmaf(a.y, b.y, acc);
                acc = fmaf(a.z, b.z, acc); acc = fmaf(a.w, b.w, acc);
            }
            float dv = (An + esq[code]) - 2.0f * acc;
            if (dv < best || (dv == best && code < bid)) { best = dv; bid = code; }
        }
        #pragma unroll
        for (int m = 1; m < 64; m <<= 1) {
            float ov = __shfl_xor(best, m); int oi = __shfl_xor(bid, m);
            if (ov < best || (ov == best && oi < bid)) { best = ov; bid = oi; }
        }
        if (lane == 0)
            atomicMin(&packed[token],
                (((unsigned long long)__float_as_uint(best)) << 32) | (unsigned)bid);
    }
}

// ------- mid: unpack idx, hist, quant gather, loss, dw atomics -------
// NO __threadfence (prior session: per-block device fence = L2 writeback on
// multi-XCD gfx950). Cross-kernel visibility via dispatch boundary.
__global__ __launch_bounds__(256) void mid_kernel(
        const float* __restrict__ z, const float* __restrict__ E,
        const unsigned long long* __restrict__ packed,
        float* __restrict__ idx_out, int* __restrict__ hist,
        float* __restrict__ dw, float* __restrict__ quant,
        float* __restrict__ loss_acc) {
    __shared__ float ls[4];
    const int wave = threadIdx.x >> 6;
    const int lane = threadIdx.x & 63;
    const int token = blockIdx.x * 4 + wave;
    const int idx = (int)(unsigned)(packed[token] & 0xFFFFFFFFull);

    if (lane == 0) {
        idx_out[token] = (float)idx;
        atomicAdd(&hist[idx], 1);
    }

    const float4 ev = *(const float4*)(E + (size_t)idx * DIM + lane * 4);
    const float4 zv = *(const float4*)(z + (size_t)token * DIM + lane * 4);
    *(float4*)(quant + (size_t)token * DIM + lane * 4) = ev;

    float* dwp = dw + (size_t)idx * DIM + lane * 4;
    atomicAdd(dwp + 0, zv.x);
    atomicAdd(dwp + 1, zv.y);
    atomicAdd(dwp + 2, zv.z);
    atomicAdd(dwp + 3, zv.w);

    float dx = zv.x - ev.x, dy = zv.y - ev.y, dz = zv.z - ev.z, dww = zv.w - ev.w;
    float l = dx * dx + dy * dy + dz * dz + dww * dww;
    #pragma unroll
    for (int off = 32; off > 0; off >>= 1) l += __shfl_down(l, off);
    if (lane == 0) ls[wave] = l;
    __syncthreads();
    if (threadIdx.x == 0)
        atomicAdd(loss_acc, ls[0] + ls[1] + ls[2] + ls[3]);
}

// ------- cs: cluster-size normalize (1 block; dispatch boundary = sync) ---
__global__ __launch_bounds__(256) void cs_kernel(
        const int* __restrict__ hist, const float* __restrict__ ema_cs,
        float* __restrict__ cs_out) {
    __shared__ float f[256];
    float pre4[4];
    float part = 0.0f;
    #pragma unroll
    for (int q = 0; q < 4; ++q) {
        int k = threadIdx.x * 4 + q;
        pre4[q] = ema_cs[k] * DECAY + (1.0f - DECAY) * (float)hist[k];
        part += pre4[q];
    }
    f[threadIdx.x] = part;
    __syncthreads();
    for (int s = 128; s > 0; s >>= 1) {
        if (threadIdx.x < s) f[threadIdx.x] += f[threadIdx.x + s];
        __syncthreads();
    }
    float n = f[0];
    #pragma unroll
    for (int q = 0; q < 4; ++q) {
        int k = threadIdx.x * 4 + q;
        cs_out[k] = (pre4[q] + EPSILON) / (n + KCODES * EPSILON) * n;
    }
}

// ------- fin: new_ema_w & new_embedding (+ loss finalize) -------
__global__ __launch_bounds__(256) void fin_kernel(
        const float* __restrict__ ema_w, const float* __restrict__ cs,
        float* __restrict__ emaw_inout /* holds dw */, float* __restrict__ emb_out,
        float* __restrict__ loss_inout) {
    const int i = blockIdx.x * 256 + threadIdx.x;   // f4 index, 65536 total
    const int k = i >> 6;
    float4 d = ((const float4*)emaw_inout)[i];
    float4 w = ((const float4*)ema_w)[i];
    float4 nw;
    nw.x = w.x * DECAY + (1.0f - DECAY) * d.x;
    nw.y = w.y * DECAY + (1.0f - DECAY) * d.y;
    nw.z = w.z * DECAY + (1.0f - DECAY) * d.z;
    nw.w = w.w * DECAY + (1.0f - DECAY) * d.w;
    ((float4*)emaw_inout)[i] = nw;
    float inv = 1.0f / cs[k];
    float4 e; e.x = nw.x * inv; e.y = nw.y * inv; e.z = nw.z * inv; e.w = nw.w * inv;
    ((float4*)emb_out)[i] = e;
    if (i == 0)
        loss_inout[0] = COMMITMENT_COST * loss_inout[0] / (float)((size_t)NTOK * DIM);
}

extern "C" void kernel_launch(void* const* d_in, const int* in_sizes, int n_in,
                              void* d_out, int out_size, void* d_ws, size_t ws_size,
                              hipStream_t stream) {
    const float* z      = (const float*)d_in[0];
    const float* E      = (const float*)d_in[1];
    const float* ema_cs = (const float*)d_in[2];
    const float* ema_w  = (const float*)d_in[3];
    float* out = (float*)d_out;

    float* emb = out + O_EMB;
    unsigned long long* packed = (unsigned long long*)(emb + SE_PACKED);
    float* esq  = emb + SE_ESQ;
    float* zsq  = emb + SE_ZSQ;
    int*   hist = (int*)(emb + SE_HIST);

    unsigned short* zh = (unsigned short*)(out + SQ_ZH);
    unsigned short* eh = (unsigned short*)(out + SQ_EH);
    unsigned long long* Mg = (unsigned long long*)(out + SQ_MG);
    int* ccount = (int*)(out + SQ_CC);
    unsigned long long* cand = (unsigned long long*)(out + SQ_CAND);

    pre_kernel<<<NTOK / 4 + KCODES / 4, 256, 0, stream>>>(
        z, E, zsq, esq, out + O_EMAW, hist, packed, out + O_LOSS,
        zh, eh, Mg, ccount);
    dist_mfma_kernel<<<(NTOK / 128) * 8, 256, 0, stream>>>(
        zh, eh, esq, Mg, ccount, cand);
    recheck_kernel<<<NTOK / 4, 256, 0, stream>>>(
        z, E, zsq, esq, Mg, ccount, cand, packed);
    mid_kernel<<<NTOK / 4, 256, 0, stream>>>(z, E, packed, out + O_IDX, hist,
                                             out + O_EMAW, out + O_QUANT,
                                             out + O_LOSS);
    cs_kernel<<<1, 256, 0, stream>>>(hist, ema_cs, out + O_CS);
    fin_kernel<<<256, 256, 0, stream>>>(ema_w, out + O_CS, out + O_EMAW, emb,
                                        out + O_LOSS);
}

// Round 2
// 544.975 us; speedup vs baseline: 8.1145x; 8.1145x over previous
//
#include <hip/hip_runtime.h>
#include <math.h>

#define COMMITMENT_COST 0.25f
#define DECAY 0.99f
#define EPSILON 1e-05f
#define KCODES 1024
#define DIM 256
#define NTOK 32768

// out-buffer float offsets (concatenated return tuple)
#define O_QUANT 0
#define O_LOSS  8388608
#define O_IDX   8388609
#define O_CS    8421377
#define O_EMAW  8422401
#define O_EMB   8684545

// scratch in the new_embedding slot (262144 floats, written LAST by fin).
// O_EMB is odd -> +1 float makes packed u64 8-byte aligned.
#define SE_PACKED 1        // u64 x 32768 -> floats [1, 65537)
#define SE_ESQ    65544
#define SE_ZSQ    66568    // 32768 floats
#define SE_HIST   99336    // 1024 ints

// scratch in the O_QUANT slot (8388608 floats, written by mid AFTER recheck).
// All consumers (dist_mfma, recheck) run before mid.
#define SQ_ZH    0         // ushort[32768*256] -> floats [0, 4194304)
#define SQ_EH    4194304   // ushort[1024*256]  -> floats [4194304, 4325376)
#define SQ_MG    4325376   // u64[32768]        -> floats [4325376, 4390912)
#define SQ_CC    4390912   // int[32768]        -> floats [4390912, 4423680)
#define SQ_CAND  4423680   // u64[32768*56]     -> floats [4423680, 8093696)

// exact-argmin recovery: candidate window threshold.
// Bound: 2*eta_ref (3.8e-5) + 2*eps_bf16 (1.6e-3) ~= 3.3e-3; theta = 3.7x margin.
// Round-1 evidence: zero argmin flips at this theta (absmax < 1).
#define THETA 0.012f
#define CAND_CAP 56

typedef __attribute__((ext_vector_type(8))) short bf16x8;
typedef __attribute__((ext_vector_type(4))) float f32x4;

__device__ __forceinline__ unsigned short f2bf(float x) {
    unsigned u = __float_as_uint(x);
    return (unsigned short)((u + 0x7FFFu + ((u >> 16) & 1u)) >> 16);  // RNE
}
__device__ __forceinline__ unsigned mono(float f) {   // order-preserving f32->u32
    unsigned u = __float_as_uint(f);
    return u ^ ((u & 0x80000000u) ? 0xFFFFFFFFu : 0x80000000u);
}
__device__ __forceinline__ float invmono(unsigned m) {
    unsigned u = m ^ ((m & 0x80000000u) ? 0x80000000u : 0xFFFFFFFFu);
    return __uint_as_float(u);
}

// ------- pre: zsq/esq, bf16 casts zh/eh, zero dw/hist/loss, init packed/Mg/cc -------
__global__ void pre_kernel(const float* __restrict__ z, const float* __restrict__ E,
                           float* __restrict__ zsq, float* __restrict__ esq,
                           float* __restrict__ dw, int* __restrict__ hist,
                           unsigned long long* __restrict__ packed,
                           float* __restrict__ loss,
                           unsigned short* __restrict__ zh,
                           unsigned short* __restrict__ eh,
                           unsigned long long* __restrict__ Mg,
                           int* __restrict__ ccount) {
    const int b = blockIdx.x;
    const int wave = threadIdx.x >> 6;
    const int lane = threadIdx.x & 63;
    if (b < NTOK / 4) {
        int token = b * 4 + wave;
        float4 v = ((const float4*)(z + (size_t)token * DIM))[lane];
        ushort4 h;
        h.x = f2bf(v.x); h.y = f2bf(v.y); h.z = f2bf(v.z); h.w = f2bf(v.w);
        *(ushort4*)(zh + (size_t)token * DIM + lane * 4) = h;
        float s = v.x * v.x + v.y * v.y + v.z * v.z + v.w * v.w;
        #pragma unroll
        for (int off = 32; off > 0; off >>= 1) s += __shfl_down(s, off);
        if (lane == 0) zsq[token] = s;
        if (threadIdx.x < 4) {
            packed[b * 4 + threadIdx.x] = ~0ull;
            Mg[b * 4 + threadIdx.x] = ~0ull;
            ccount[b * 4 + threadIdx.x] = 0;
        }
        if (b == 0 && threadIdx.x == 4) loss[0] = 0.0f;
    } else {
        int eb = b - NTOK / 4;                 // 0..255
        int k = eb * 4 + wave;
        float4 v = ((const float4*)(E + (size_t)k * DIM))[lane];
        ushort4 h;
        h.x = f2bf(v.x); h.y = f2bf(v.y); h.z = f2bf(v.z); h.w = f2bf(v.w);
        *(ushort4*)(eh + (size_t)k * DIM + lane * 4) = h;
        float s = v.x * v.x + v.y * v.y + v.z * v.z + v.w * v.w;
        #pragma unroll
        for (int off = 32; off > 0; off >>= 1) s += __shfl_down(s, off);
        if (lane == 0) esq[k] = s;
        float4 zero4 = {0.f, 0.f, 0.f, 0.f};
        ((float4*)dw)[eb * 256 + threadIdx.x] = zero4;
        if (threadIdx.x < 4) hist[eb * 4 + threadIdx.x] = 0;
    }
}

// ---------------- bf16 MFMA approximate-distance pass ----------------
// delta~(t,j) = esq[j] - 2 * (zh . eh)  via mfma_f32_16x16x32_bf16.
// Tile 128 tok x 128 codes, BK=32, 4 waves (2x2), 4x4 16x16 frags/wave.
// Grid remap: toktile = bid & 255, chunk = bid >> 8 -> the 8 code-chunks of
// a token run in DIFFERENT dispatch waves; early chunks seed Mg so late
// chunks emit against the global min (emission ~0.7/tile vs 5.4 tile-local).
// atomicMin returns OLD -> effective known-global-min = min(block_min, old);
// correctness: for any real recorded d~(j), d~(j*) <= d~(j) + 2*Delta.
__global__ __launch_bounds__(256) void dist_mfma_kernel(
        const unsigned short* __restrict__ zh, const unsigned short* __restrict__ eh,
        const float* __restrict__ esq,
        unsigned long long* __restrict__ Mg, int* __restrict__ ccount,
        unsigned long long* __restrict__ cand) {
    __shared__ unsigned short Als[128 * 40];
    __shared__ unsigned short Bls[128 * 40];
    __shared__ unsigned long long scr[128][2];

    const int tid = threadIdx.x;
    const int wid = tid >> 6;
    const int lane = tid & 63;
    const int wm = wid >> 1, wn = wid & 1;
    const int l15 = lane & 15, l4 = lane >> 4;
    const int tok0 = (blockIdx.x & 255) * 128;
    const int c0 = (blockIdx.x >> 8) * 128;

    // staging: thread covers rows srow, srow+64 at element col gc8..gc8+7
    const int srow = tid >> 2;              // 0..63
    const int gc8 = (tid & 3) * 8;
    const unsigned short* zsrc = zh + (size_t)(tok0 + srow) * 256 + gc8;
    const unsigned short* esrc = eh + (size_t)(c0 + srow) * 256 + gc8;
    unsigned short* adst = Als + srow * 40 + gc8;
    unsigned short* bdst = Bls + srow * 40 + gc8;

    f32x4 acc[4][4];
    #pragma unroll
    for (int i = 0; i < 4; ++i)
        #pragma unroll
        for (int j = 0; j < 4; ++j)
            acc[i][j] = (f32x4){0.f, 0.f, 0.f, 0.f};

    for (int kt = 0; kt < 8; ++kt) {
        const int kk = kt * 32;
        // issue global loads BEFORE the barrier: latency hides under the wait
        bf16x8 a0 = *(const bf16x8*)(zsrc + kk);
        bf16x8 a1 = *(const bf16x8*)(zsrc + 64 * 256 + kk);
        bf16x8 b0 = *(const bf16x8*)(esrc + kk);
        bf16x8 b1 = *(const bf16x8*)(esrc + 64 * 256 + kk);
        __syncthreads();                    // previous iter's frag reads done
        *(bf16x8*)adst = a0;
        *(bf16x8*)(adst + 64 * 40) = a1;
        *(bf16x8*)bdst = b0;
        *(bf16x8*)(bdst + 64 * 40) = b1;
        __syncthreads();
        // fragments: A row = lane&15, k = (lane>>4)*8 + i (contiguous 8 bf16);
        // B symmetric (col = lane&15). C/D: col=lane&15, row=(lane>>4)*4+reg.
        bf16x8 av[4], bv[4];
        #pragma unroll
        for (int f = 0; f < 4; ++f) {
            av[f] = *(const bf16x8*)(Als + (wm * 64 + f * 16 + l15) * 40 + l4 * 8);
            bv[f] = *(const bf16x8*)(Bls + (wn * 64 + f * 16 + l15) * 40 + l4 * 8);
        }
        #pragma unroll
        for (int i = 0; i < 4; ++i)
            #pragma unroll
            for (int j = 0; j < 4; ++j)
                acc[i][j] = __builtin_amdgcn_mfma_f32_16x16x32_bf16(
                    av[i], bv[j], acc[i][j], 0, 0, 0);
    }

    // epilogue: delta~ = sq[j] - 2*acc; per-row min; share via Mg; window emit
    float sq[4];
    #pragma unroll
    for (int j = 0; j < 4; ++j) sq[j] = esq[c0 + wn * 64 + j * 16 + l15];

    #pragma unroll
    for (int i = 0; i < 4; ++i) {
        #pragma unroll
        for (int r = 0; r < 4; ++r) {
            float v = 3.4e38f;
            #pragma unroll
            for (int j = 0; j < 4; ++j)
                v = fminf(v, sq[j] - 2.0f * acc[i][j][r]);
            #pragma unroll
            for (int m = 1; m < 16; m <<= 1)
                v = fminf(v, __shfl_xor(v, m));
            if (l15 == 0)
                scr[wm * 64 + i * 16 + l4 * 4 + r][wn] =
                    ((unsigned long long)mono(v)) << 32;
        }
    }
    __syncthreads();
    if (tid < 128) {
        unsigned long long a = scr[tid][0], b = scr[tid][1];
        unsigned long long mn = a < b ? a : b;
        unsigned long long old = atomicMin(&Mg[tok0 + tid], mn);
        scr[tid][0] = old < mn ? old : mn;   // best globally-known min
    }
    __syncthreads();
    #pragma unroll
    for (int i = 0; i < 4; ++i) {
        #pragma unroll
        for (int r = 0; r < 4; ++r) {
            const int rowl = wm * 64 + i * 16 + l4 * 4 + r;
            const float thr = invmono((unsigned)(scr[rowl][0] >> 32)) + THETA;
            #pragma unroll
            for (int j = 0; j < 4; ++j) {
                float d = sq[j] - 2.0f * acc[i][j][r];
                if (d <= thr) {
                    int token = tok0 + rowl;
                    int slot = atomicAdd(&ccount[token], 1);
                    if (slot < CAND_CAP)
                        cand[(size_t)token * CAND_CAP + slot] =
                            (((unsigned long long)__float_as_uint(d)) << 32) |
                            (unsigned)(c0 + wn * 64 + j * 16 + l15);
                }
            }
        }
    }
}

// ------- recheck: exact fp32 dv for filtered candidates, ref-order ----------
// dv = fl(fl(An + sq) - 2*acc), acc = seq fmaf over d ascending (x,y,z,w) —
// bit-identical to the passing fp32 kernel's epilogue. Packed
// (dv_bits<<32)|idx u64 atomicMin reproduces first-index tie-break.
// Overflow (ccount > CAND_CAP, now rare): full exact 1024-code scan fallback.
__global__ __launch_bounds__(256) void recheck_kernel(
        const float* __restrict__ z, const float* __restrict__ E,
        const float* __restrict__ zsq, const float* __restrict__ esq,
        const unsigned long long* __restrict__ Mg, const int* __restrict__ ccount,
        const unsigned long long* __restrict__ cand,
        unsigned long long* __restrict__ packed) {
    const int wave = threadIdx.x >> 6, lane = threadIdx.x & 63;
    const int token = blockIdx.x * 4 + wave;
    const int cnt = ccount[token];
    const float Mt = invmono((unsigned)(Mg[token] >> 32));
    const float An = zsq[token];
    const float4* zp = (const float4*)(z + (size_t)token * 256);

    if (cnt <= CAND_CAP) {
        if (lane < cnt) {
            unsigned long long e = cand[(size_t)token * CAND_CAP + lane];
            float dt = __uint_as_float((unsigned)(e >> 32));
            int code = (int)(unsigned)(e & 0xFFFFFFFFull);
            if (dt <= Mt + THETA) {
                const float4* ep = (const float4*)(E + (size_t)code * 256);
                float acc = 0.0f;
                #pragma unroll 8
                for (int q = 0; q < 64; ++q) {
                    float4 a = zp[q], b = ep[q];
                    acc = fmaf(a.x, b.x, acc); acc = fmaf(a.y, b.y, acc);
                    acc = fmaf(a.z, b.z, acc); acc = fmaf(a.w, b.w, acc);
                }
                float S = An + esq[code];
                float dv = S - 2.0f * acc;
                atomicMin(&packed[token],
                    (((unsigned long long)__float_as_uint(dv)) << 32) | (unsigned)code);
            }
        }
    } else {
        float best = 3.4e38f; int bid = 0x7fffffff;
        for (int code = lane; code < KCODES; code += 64) {
            const float4* ep = (const float4*)(E + (size_t)code * 256);
            float acc = 0.0f;
            for (int q = 0; q < 64; ++q) {
                float4 a = zp[q], b = ep[q];
                acc = fmaf(a.x, b.x, acc); acc = fmaf(a.y, b.y, acc);
                acc = fmaf(a.z, b.z, acc); acc = fmaf(a.w, b.w, acc);
            }
            float dv = (An + esq[code]) - 2.0f * acc;
            if (dv < best || (dv == best && code < bid)) { best = dv; bid = code; }
        }
        #pragma unroll
        for (int m = 1; m < 64; m <<= 1) {
            float ov = __shfl_xor(best, m); int oi = __shfl_xor(bid, m);
            if (ov < best || (ov == best && oi < bid)) { best = ov; bid = oi; }
        }
        if (lane == 0)
            atomicMin(&packed[token],
                (((unsigned long long)__float_as_uint(best)) << 32) | (unsigned)bid);
    }
}

// ------- mid: unpack idx, hist, quant gather, loss, dw atomics -------
// NO __threadfence (prior session: per-block device fence = L2 writeback on
// multi-XCD gfx950). Cross-kernel visibility via dispatch boundary.
__global__ __launch_bounds__(256) void mid_kernel(
        const float* __restrict__ z, const float* __restrict__ E,
        const unsigned long long* __restrict__ packed,
        float* __restrict__ idx_out, int* __restrict__ hist,
        float* __restrict__ dw, float* __restrict__ quant,
        float* __restrict__ loss_acc) {
    __shared__ float ls[4];
    const int wave = threadIdx.x >> 6;
    const int lane = threadIdx.x & 63;
    const int token = blockIdx.x * 4 + wave;
    const int idx = (int)(unsigned)(packed[token] & 0xFFFFFFFFull);

    if (lane == 0) {
        idx_out[token] = (float)idx;
        atomicAdd(&hist[idx], 1);
    }

    const float4 ev = *(const float4*)(E + (size_t)idx * DIM + lane * 4);
    const float4 zv = *(const float4*)(z + (size_t)token * DIM + lane * 4);
    *(float4*)(quant + (size_t)token * DIM + lane * 4) = ev;

    float* dwp = dw + (size_t)idx * DIM + lane * 4;
    atomicAdd(dwp + 0, zv.x);
    atomicAdd(dwp + 1, zv.y);
    atomicAdd(dwp + 2, zv.z);
    atomicAdd(dwp + 3, zv.w);

    float dx = zv.x - ev.x, dy = zv.y - ev.y, dz = zv.z - ev.z, dww = zv.w - ev.w;
    float l = dx * dx + dy * dy + dz * dz + dww * dww;
    #pragma unroll
    for (int off = 32; off > 0; off >>= 1) l += __shfl_down(l, off);
    if (lane == 0) ls[wave] = l;
    __syncthreads();
    if (threadIdx.x == 0)
        atomicAdd(loss_acc, ls[0] + ls[1] + ls[2] + ls[3]);
}

// ------- cs: cluster-size normalize (1 block; dispatch boundary = sync) ---
__global__ __launch_bounds__(256) void cs_kernel(
        const int* __restrict__ hist, const float* __restrict__ ema_cs,
        float* __restrict__ cs_out) {
    __shared__ float f[256];
    float pre4[4];
    float part = 0.0f;
    #pragma unroll
    for (int q = 0; q < 4; ++q) {
        int k = threadIdx.x * 4 + q;
        pre4[q] = ema_cs[k] * DECAY + (1.0f - DECAY) * (float)hist[k];
        part += pre4[q];
    }
    f[threadIdx.x] = part;
    __syncthreads();
    for (int s = 128; s > 0; s >>= 1) {
        if (threadIdx.x < s) f[threadIdx.x] += f[threadIdx.x + s];
        __syncthreads();
    }
    float n = f[0];
    #pragma unroll
    for (int q = 0; q < 4; ++q) {
        int k = threadIdx.x * 4 + q;
        cs_out[k] = (pre4[q] + EPSILON) / (n + KCODES * EPSILON) * n;
    }
}

// ------- fin: new_ema_w & new_embedding (+ loss finalize) -------
__global__ __launch_bounds__(256) void fin_kernel(
        const float* __restrict__ ema_w, const float* __restrict__ cs,
        float* __restrict__ emaw_inout /* holds dw */, float* __restrict__ emb_out,
        float* __restrict__ loss_inout) {
    const int i = blockIdx.x * 256 + threadIdx.x;   // f4 index, 65536 total
    const int k = i >> 6;
    float4 d = ((const float4*)emaw_inout)[i];
    float4 w = ((const float4*)ema_w)[i];
    float4 nw;
    nw.x = w.x * DECAY + (1.0f - DECAY) * d.x;
    nw.y = w.y * DECAY + (1.0f - DECAY) * d.y;
    nw.z = w.z * DECAY + (1.0f - DECAY) * d.z;
    nw.w = w.w * DECAY + (1.0f - DECAY) * d.w;
    ((float4*)emaw_inout)[i] = nw;
    float inv = 1.0f / cs[k];
    float4 e; e.x = nw.x * inv; e.y = nw.y * inv; e.z = nw.z * inv; e.w = nw.w * inv;
    ((float4*)emb_out)[i] = e;
    if (i == 0)
        loss_inout[0] = COMMITMENT_COST * loss_inout[0] / (float)((size_t)NTOK * DIM);
}

extern "C" void kernel_launch(void* const* d_in, const int* in_sizes, int n_in,
                              void* d_out, int out_size, void* d_ws, size_t ws_size,
                              hipStream_t stream) {
    const float* z      = (const float*)d_in[0];
    const float* E      = (const float*)d_in[1];
    const float* ema_cs = (const float*)d_in[2];
    const float* ema_w  = (const float*)d_in[3];
    float* out = (float*)d_out;

    float* emb = out + O_EMB;
    unsigned long long* packed = (unsigned long long*)(emb + SE_PACKED);
    float* esq  = emb + SE_ESQ;
    float* zsq  = emb + SE_ZSQ;
    int*   hist = (int*)(emb + SE_HIST);

    unsigned short* zh = (unsigned short*)(out + SQ_ZH);
    unsigned short* eh = (unsigned short*)(out + SQ_EH);
    unsigned long long* Mg = (unsigned long long*)(out + SQ_MG);
    int* ccount = (int*)(out + SQ_CC);
    unsigned long long* cand = (unsigned long long*)(out + SQ_CAND);

    pre_kernel<<<NTOK / 4 + KCODES / 4, 256, 0, stream>>>(
        z, E, zsq, esq, out + O_EMAW, hist, packed, out + O_LOSS,
        zh, eh, Mg, ccount);
    dist_mfma_kernel<<<(NTOK / 128) * 8, 256, 0, stream>>>(
        zh, eh, esq, Mg, ccount, cand);
    recheck_kernel<<<NTOK / 4, 256, 0, stream>>>(
        z, E, zsq, esq, Mg, ccount, cand, packed);
    mid_kernel<<<NTOK / 4, 256, 0, stream>>>(z, E, packed, out + O_IDX, hist,
                                             out + O_EMAW, out + O_QUANT,
                                             out + O_LOSS);
    cs_kernel<<<1, 256, 0, stream>>>(hist, ema_cs, out + O_CS);
    fin_kernel<<<256, 256, 0, stream>>>(ema_w, out + O_CS, out + O_EMAW, emb,
                                        out + O_LOSS);
}

// Round 3
// 524.585 us; speedup vs baseline: 8.4299x; 1.0389x over previous
//
#include <hip/hip_runtime.h>
#include <math.h>

#define COMMITMENT_COST 0.25f
#define DECAY 0.99f
#define EPSILON 1e-05f
#define KCODES 1024
#define DIM 256
#define NTOK 32768

// out-buffer float offsets (concatenated return tuple)
#define O_QUANT 0
#define O_LOSS  8388608
#define O_IDX   8388609
#define O_CS    8421377
#define O_EMAW  8422401
#define O_EMB   8684545

// scratch in the new_embedding slot (262144 floats, written LAST by fin).
// O_EMB is odd -> +1 float makes packed u64 8-byte aligned.
#define SE_PACKED 1        // u64 x 32768 -> floats [1, 65537)
#define SE_ESQ    65544
#define SE_ZSQ    66568    // 32768 floats
#define SE_HIST   99336    // 1024 ints
#define SE_NP     100360   // 1 int: pair count
#define SE_NOVF   100361   // 1 int: overflow-token count
#define SE_OVF    100362   // 32768 ints -> ends 133130 < 262144

// scratch in the O_QUANT slot (8388608 floats, written by mid AFTER recheck).
// All consumers (dist_mfma, recheck_a/b) run before mid.
#define SQ_ZH    0         // ushort[32768*256] -> floats [0, 4194304)
#define SQ_EH    4194304   // ushort[1024*256]  -> floats [4194304, 4325376)
#define SQ_MG    4325376   // u64[32768]        -> floats [4325376, 4390912)
#define SQ_CC    4390912   // int[32768]        -> floats [4390912, 4423680)
#define SQ_CAND  4423680   // u64[56][32768] TRANSPOSED -> floats [4423680, 8093696)
#define SQ_PAIRS 8093696   // u32[262144]       -> floats [8093696, 8355840)

// exact-argmin recovery thresholds.
// Emission window (dist): THETA = 0.012 (round-1/2 validated, zero flips).
// Filter window (recheck_a): THETA_F = 0.008 >= conservative 2*Delta ~ 4.7e-3
// (bf16 RNE eps 2^-8, Sum|z_i||e_i| <= ||z||*||e|| ~ 0.144, x2 distance factor,
// x2 both-sides, + ref-rounding eta ~ 7e-5). Superset property: emission thr
// >= Mt + THETA > Mt + THETA_F, so the filtered set is exactly
// {j : d~(j) <= Mt+THETA_F}, which provably contains the reference argmin.
#define THETA 0.012f
#define THETA_F 0.008f
#define CAND_CAP 56
#define PAIR_CAP 262144

typedef __attribute__((ext_vector_type(8))) short bf16x8;
typedef __attribute__((ext_vector_type(4))) float f32x4;

__device__ __forceinline__ unsigned short f2bf(float x) {
    unsigned u = __float_as_uint(x);
    return (unsigned short)((u + 0x7FFFu + ((u >> 16) & 1u)) >> 16);  // RNE
}
__device__ __forceinline__ unsigned mono(float f) {   // order-preserving f32->u32
    unsigned u = __float_as_uint(f);
    return u ^ ((u & 0x80000000u) ? 0xFFFFFFFFu : 0x80000000u);
}
__device__ __forceinline__ float invmono(unsigned m) {
    unsigned u = m ^ ((m & 0x80000000u) ? 0x80000000u : 0xFFFFFFFFu);
    return __uint_as_float(u);
}

// exact fp32 distance, bit-identical to the passing rounds' recheck order:
// seq fmaf q=0..63 (x,y,z,w), S = An + esq, dv = S - 2*acc. Positive ->
// float-bit order works; packed (dv<<32)|idx atomicMin = first-index ties.
__device__ __forceinline__ void exact_min_update(
        const float* __restrict__ z, const float* __restrict__ E,
        const float* __restrict__ zsq, const float* __restrict__ esq,
        int token, int code, unsigned long long* __restrict__ packed) {
    const float4* zp = (const float4*)(z + (size_t)token * DIM);
    const float4* ep = (const float4*)(E + (size_t)code * DIM);
    float acc = 0.0f;
    #pragma unroll 8
    for (int q = 0; q < 64; ++q) {
        float4 a = zp[q], b = ep[q];
        acc = fmaf(a.x, b.x, acc); acc = fmaf(a.y, b.y, acc);
        acc = fmaf(a.z, b.z, acc); acc = fmaf(a.w, b.w, acc);
    }
    float S = zsq[token] + esq[code];
    float dv = S - 2.0f * acc;
    atomicMin(&packed[token],
        (((unsigned long long)__float_as_uint(dv)) << 32) | (unsigned)code);
}

// ------- pre: zsq/esq, bf16 casts zh/eh, zero dw/hist/loss/counters, init -------
__global__ void pre_kernel(const float* __restrict__ z, const float* __restrict__ E,
                           float* __restrict__ zsq, float* __restrict__ esq,
                           float* __restrict__ dw, int* __restrict__ hist,
                           unsigned long long* __restrict__ packed,
                           float* __restrict__ loss,
                           unsigned short* __restrict__ zh,
                           unsigned short* __restrict__ eh,
                           unsigned long long* __restrict__ Mg,
                           int* __restrict__ ccount,
                           int* __restrict__ npairs, int* __restrict__ novf) {
    const int b = blockIdx.x;
    const int wave = threadIdx.x >> 6;
    const int lane = threadIdx.x & 63;
    if (b < NTOK / 4) {
        int token = b * 4 + wave;
        float4 v = ((const float4*)(z + (size_t)token * DIM))[lane];
        ushort4 h;
        h.x = f2bf(v.x); h.y = f2bf(v.y); h.z = f2bf(v.z); h.w = f2bf(v.w);
        *(ushort4*)(zh + (size_t)token * DIM + lane * 4) = h;
        float s = v.x * v.x + v.y * v.y + v.z * v.z + v.w * v.w;
        #pragma unroll
        for (int off = 32; off > 0; off >>= 1) s += __shfl_down(s, off);
        if (lane == 0) zsq[token] = s;
        if (threadIdx.x < 4) {
            packed[b * 4 + threadIdx.x] = ~0ull;
            Mg[b * 4 + threadIdx.x] = ~0ull;
            ccount[b * 4 + threadIdx.x] = 0;
        }
        if (b == 0 && threadIdx.x == 4) loss[0] = 0.0f;
        if (b == 0 && threadIdx.x == 5) { *npairs = 0; *novf = 0; }
    } else {
        int eb = b - NTOK / 4;                 // 0..255
        int k = eb * 4 + wave;
        float4 v = ((const float4*)(E + (size_t)k * DIM))[lane];
        ushort4 h;
        h.x = f2bf(v.x); h.y = f2bf(v.y); h.z = f2bf(v.z); h.w = f2bf(v.w);
        *(ushort4*)(eh + (size_t)k * DIM + lane * 4) = h;
        float s = v.x * v.x + v.y * v.y + v.z * v.z + v.w * v.w;
        #pragma unroll
        for (int off = 32; off > 0; off >>= 1) s += __shfl_down(s, off);
        if (lane == 0) esq[k] = s;
        float4 zero4 = {0.f, 0.f, 0.f, 0.f};
        ((float4*)dw)[eb * 256 + threadIdx.x] = zero4;
        if (threadIdx.x < 4) hist[eb * 4 + threadIdx.x] = 0;
    }
}

// ---------------- bf16 MFMA approximate-distance pass ----------------
// delta~(t,j) = esq[j] - 2 * (zh . eh)  via mfma_f32_16x16x32_bf16.
// Tile 128 tok x 128 codes, BK=32, 4 waves (2x2), 4x4 16x16 frags/wave.
// Grid remap: toktile = bid & 255, chunk = bid >> 8 -> the 8 code-chunks of
// a token run in DIFFERENT dispatch waves; early chunks seed Mg so late
// chunks emit against the global min. cand layout TRANSPOSED [slot][NTOK]
// so recheck_a's per-token scan is coalesced.
__global__ __launch_bounds__(256) void dist_mfma_kernel(
        const unsigned short* __restrict__ zh, const unsigned short* __restrict__ eh,
        const float* __restrict__ esq,
        unsigned long long* __restrict__ Mg, int* __restrict__ ccount,
        unsigned long long* __restrict__ cand) {
    __shared__ unsigned short Als[128 * 40];
    __shared__ unsigned short Bls[128 * 40];
    __shared__ unsigned long long scr[128][2];

    const int tid = threadIdx.x;
    const int wid = tid >> 6;
    const int lane = tid & 63;
    const int wm = wid >> 1, wn = wid & 1;
    const int l15 = lane & 15, l4 = lane >> 4;
    const int tok0 = (blockIdx.x & 255) * 128;
    const int c0 = (blockIdx.x >> 8) * 128;

    // staging: thread covers rows srow, srow+64 at element col gc8..gc8+7
    const int srow = tid >> 2;              // 0..63
    const int gc8 = (tid & 3) * 8;
    const unsigned short* zsrc = zh + (size_t)(tok0 + srow) * 256 + gc8;
    const unsigned short* esrc = eh + (size_t)(c0 + srow) * 256 + gc8;
    unsigned short* adst = Als + srow * 40 + gc8;
    unsigned short* bdst = Bls + srow * 40 + gc8;

    f32x4 acc[4][4];
    #pragma unroll
    for (int i = 0; i < 4; ++i)
        #pragma unroll
        for (int j = 0; j < 4; ++j)
            acc[i][j] = (f32x4){0.f, 0.f, 0.f, 0.f};

    for (int kt = 0; kt < 8; ++kt) {
        const int kk = kt * 32;
        // issue global loads BEFORE the barrier: latency hides under the wait
        bf16x8 a0 = *(const bf16x8*)(zsrc + kk);
        bf16x8 a1 = *(const bf16x8*)(zsrc + 64 * 256 + kk);
        bf16x8 b0 = *(const bf16x8*)(esrc + kk);
        bf16x8 b1 = *(const bf16x8*)(esrc + 64 * 256 + kk);
        __syncthreads();                    // previous iter's frag reads done
        *(bf16x8*)adst = a0;
        *(bf16x8*)(adst + 64 * 40) = a1;
        *(bf16x8*)bdst = b0;
        *(bf16x8*)(bdst + 64 * 40) = b1;
        __syncthreads();
        // fragments: A row = lane&15, k = (lane>>4)*8 + i (contiguous 8 bf16);
        // B symmetric (col = lane&15). C/D: col=lane&15, row=(lane>>4)*4+reg.
        bf16x8 av[4], bv[4];
        #pragma unroll
        for (int f = 0; f < 4; ++f) {
            av[f] = *(const bf16x8*)(Als + (wm * 64 + f * 16 + l15) * 40 + l4 * 8);
            bv[f] = *(const bf16x8*)(Bls + (wn * 64 + f * 16 + l15) * 40 + l4 * 8);
        }
        #pragma unroll
        for (int i = 0; i < 4; ++i)
            #pragma unroll
            for (int j = 0; j < 4; ++j)
                acc[i][j] = __builtin_amdgcn_mfma_f32_16x16x32_bf16(
                    av[i], bv[j], acc[i][j], 0, 0, 0);
    }

    // epilogue: delta~ = sq[j] - 2*acc; per-row min; share via Mg; window emit
    float sq[4];
    #pragma unroll
    for (int j = 0; j < 4; ++j) sq[j] = esq[c0 + wn * 64 + j * 16 + l15];

    #pragma unroll
    for (int i = 0; i < 4; ++i) {
        #pragma unroll
        for (int r = 0; r < 4; ++r) {
            float v = 3.4e38f;
            #pragma unroll
            for (int j = 0; j < 4; ++j)
                v = fminf(v, sq[j] - 2.0f * acc[i][j][r]);
            #pragma unroll
            for (int m = 1; m < 16; m <<= 1)
                v = fminf(v, __shfl_xor(v, m));
            if (l15 == 0)
                scr[wm * 64 + i * 16 + l4 * 4 + r][wn] =
                    ((unsigned long long)mono(v)) << 32;
        }
    }
    __syncthreads();
    if (tid < 128) {
        unsigned long long a = scr[tid][0], b = scr[tid][1];
        unsigned long long mn = a < b ? a : b;
        unsigned long long old = atomicMin(&Mg[tok0 + tid], mn);
        scr[tid][0] = old < mn ? old : mn;   // best globally-known min
    }
    __syncthreads();
    #pragma unroll
    for (int i = 0; i < 4; ++i) {
        #pragma unroll
        for (int r = 0; r < 4; ++r) {
            const int rowl = wm * 64 + i * 16 + l4 * 4 + r;
            const float thr = invmono((unsigned)(scr[rowl][0] >> 32)) + THETA;
            #pragma unroll
            for (int j = 0; j < 4; ++j) {
                float d = sq[j] - 2.0f * acc[i][j][r];
                if (d <= thr) {
                    int token = tok0 + rowl;
                    int slot = atomicAdd(&ccount[token], 1);
                    if (slot < CAND_CAP)
                        cand[(size_t)slot * NTOK + token] =
                            (((unsigned long long)__float_as_uint(d)) << 32) |
                            (unsigned)(c0 + wn * 64 + j * 16 + l15);
                }
            }
        }
    }
}

// ------- recheck_a: per-TOKEN filter; 1 survivor -> direct write; ----------
// >=2 -> emit pairs (block-aggregated reservation). Overflow -> ovf list.
// Single-survivor proof: the only code with d~ <= Mt+THETA_F must be the
// exact reference argmin (all others have strictly larger reference dist);
// ref ties always produce >=2 survivors, so no tie-break is skipped.
__global__ __launch_bounds__(256) void recheck_a_kernel(
        const unsigned long long* __restrict__ Mg, const int* __restrict__ ccount,
        const unsigned long long* __restrict__ cand,
        unsigned long long* __restrict__ packed,
        unsigned int* __restrict__ pairs, int* __restrict__ npairs,
        int* __restrict__ ovf, int* __restrict__ novf,
        const float* __restrict__ z, const float* __restrict__ E,
        const float* __restrict__ zsq, const float* __restrict__ esq) {
    __shared__ int ps[256];
    __shared__ int base_s;
    const int tid = threadIdx.x;
    const int token = blockIdx.x * 256 + tid;
    const int cnt = ccount[token];
    const float thr = invmono((unsigned)(Mg[token] >> 32)) + THETA_F;

    int nsurv = 0;
    int firstcode = 0;
    if (cnt > CAND_CAP) {
        int s = atomicAdd(novf, 1);
        ovf[s] = token;
    } else {
        for (int s = 0; s < cnt; ++s) {
            unsigned long long e = cand[(size_t)s * NTOK + token];
            float dt = __uint_as_float((unsigned)(e >> 32));
            if (dt <= thr) {
                ++nsurv;
                if (nsurv == 1) firstcode = (int)(unsigned)(e & 0xFFFFFFFFull);
            }
        }
    }
    const int want = (cnt <= CAND_CAP && nsurv >= 2) ? nsurv : 0;

    // block inclusive prefix-sum of want -> one atomicAdd per block
    ps[tid] = want;
    __syncthreads();
    #pragma unroll
    for (int off = 1; off < 256; off <<= 1) {
        int v = (tid >= off) ? ps[tid - off] : 0;
        __syncthreads();
        ps[tid] += v;
        __syncthreads();
    }
    if (tid == 255) base_s = atomicAdd(npairs, ps[255]);
    __syncthreads();
    const int base = base_s + ps[tid] - want;

    if (cnt <= CAND_CAP) {
        if (nsurv == 1) {
            packed[token] = (unsigned long long)(unsigned)firstcode;  // low32=idx
        } else if (nsurv >= 2) {
            if (base + nsurv <= PAIR_CAP) {
                int w = 0;
                for (int s = 0; s < cnt; ++s) {
                    unsigned long long e = cand[(size_t)s * NTOK + token];
                    float dt = __uint_as_float((unsigned)(e >> 32));
                    if (dt <= thr)
                        pairs[base + (w++)] =
                            ((unsigned)token << 10) |
                            (unsigned)(e & 0x3FFull);
                }
            } else {
                // pair-list overflow (expected never): sentinel the reserved
                // in-range slots, process survivors inline (exact, correct).
                for (int i = base; i < PAIR_CAP && i < base + nsurv; ++i)
                    pairs[i] = 0xFFFFFFFFu;
                for (int s = 0; s < cnt; ++s) {
                    unsigned long long e = cand[(size_t)s * NTOK + token];
                    float dt = __uint_as_float((unsigned)(e >> 32));
                    if (dt <= thr)
                        exact_min_update(z, E, zsq, esq, token,
                                         (int)(unsigned)(e & 0x3FFull), packed);
                }
            }
        }
    }
}

// ------- recheck_b: one LANE per (token,code) pair: exact ref-order dot ----
// Blocks [0,224): grid-stride pairs. Blocks [224,256): wave-per-overflow-token
// full 1024-code exact scan (expected 0 -> instant exit).
__global__ __launch_bounds__(256) void recheck_b_kernel(
        const float* __restrict__ z, const float* __restrict__ E,
        const float* __restrict__ zsq, const float* __restrict__ esq,
        const unsigned int* __restrict__ pairs, const int* __restrict__ npairs,
        const int* __restrict__ ovf, const int* __restrict__ novf,
        unsigned long long* __restrict__ packed) {
    if (blockIdx.x < 224) {
        int n = *npairs;
        if (n > PAIR_CAP) n = PAIR_CAP;
        for (int i = blockIdx.x * 256 + threadIdx.x; i < n; i += 224 * 256) {
            unsigned p = pairs[i];
            if (p == 0xFFFFFFFFu) continue;
            exact_min_update(z, E, zsq, esq, (int)(p >> 10), (int)(p & 1023u),
                             packed);
        }
    } else {
        const int n = *novf;
        const int lane = threadIdx.x & 63;
        int w = (blockIdx.x - 224) * 4 + (threadIdx.x >> 6);
        for (; w < n; w += 32 * 4) {
            const int token = ovf[w];
            const float An = zsq[token];
            const float4* zp = (const float4*)(z + (size_t)token * DIM);
            float best = 3.4e38f; int bid = 0x7fffffff;
            for (int code = lane; code < KCODES; code += 64) {
                const float4* ep = (const float4*)(E + (size_t)code * DIM);
                float acc = 0.0f;
                for (int q = 0; q < 64; ++q) {
                    float4 a = zp[q], b = ep[q];
                    acc = fmaf(a.x, b.x, acc); acc = fmaf(a.y, b.y, acc);
                    acc = fmaf(a.z, b.z, acc); acc = fmaf(a.w, b.w, acc);
                }
                float dv = (An + esq[code]) - 2.0f * acc;
                if (dv < best || (dv == best && code < bid)) { best = dv; bid = code; }
            }
            #pragma unroll
            for (int m = 1; m < 64; m <<= 1) {
                float ov = __shfl_xor(best, m); int oi = __shfl_xor(bid, m);
                if (ov < best || (ov == best && oi < bid)) { best = ov; bid = oi; }
            }
            if (lane == 0)
                atomicMin(&packed[token],
                    (((unsigned long long)__float_as_uint(best)) << 32) |
                    (unsigned)bid);
        }
    }
}

// ------- mid: unpack idx, hist, quant gather, loss, dw atomics -------
// NO __threadfence (prior session: per-block device fence = L2 writeback on
// multi-XCD gfx950). Cross-kernel visibility via dispatch boundary.
__global__ __launch_bounds__(256) void mid_kernel(
        const float* __restrict__ z, const float* __restrict__ E,
        const unsigned long long* __restrict__ packed,
        float* __restrict__ idx_out, int* __restrict__ hist,
        float* __restrict__ dw, float* __restrict__ quant,
        float* __restrict__ loss_acc) {
    __shared__ float ls[4];
    const int wave = threadIdx.x >> 6;
    const int lane = threadIdx.x & 63;
    const int token = blockIdx.x * 4 + wave;
    const int idx = (int)(unsigned)(packed[token] & 0xFFFFFFFFull);

    if (lane == 0) {
        idx_out[token] = (float)idx;
        atomicAdd(&hist[idx], 1);
    }

    const float4 ev = *(const float4*)(E + (size_t)idx * DIM + lane * 4);
    const float4 zv = *(const float4*)(z + (size_t)token * DIM + lane * 4);
    *(float4*)(quant + (size_t)token * DIM + lane * 4) = ev;

    float* dwp = dw + (size_t)idx * DIM + lane * 4;
    atomicAdd(dwp + 0, zv.x);
    atomicAdd(dwp + 1, zv.y);
    atomicAdd(dwp + 2, zv.z);
    atomicAdd(dwp + 3, zv.w);

    float dx = zv.x - ev.x, dy = zv.y - ev.y, dz = zv.z - ev.z, dww = zv.w - ev.w;
    float l = dx * dx + dy * dy + dz * dz + dww * dww;
    #pragma unroll
    for (int off = 32; off > 0; off >>= 1) l += __shfl_down(l, off);
    if (lane == 0) ls[wave] = l;
    __syncthreads();
    if (threadIdx.x == 0)
        atomicAdd(loss_acc, ls[0] + ls[1] + ls[2] + ls[3]);
}

// ------- cs: cluster-size normalize (1 block; dispatch boundary = sync) ---
__global__ __launch_bounds__(256) void cs_kernel(
        const int* __restrict__ hist, const float* __restrict__ ema_cs,
        float* __restrict__ cs_out) {
    __shared__ float f[256];
    float pre4[4];
    float part = 0.0f;
    #pragma unroll
    for (int q = 0; q < 4; ++q) {
        int k = threadIdx.x * 4 + q;
        pre4[q] = ema_cs[k] * DECAY + (1.0f - DECAY) * (float)hist[k];
        part += pre4[q];
    }
    f[threadIdx.x] = part;
    __syncthreads();
    for (int s = 128; s > 0; s >>= 1) {
        if (threadIdx.x < s) f[threadIdx.x] += f[threadIdx.x + s];
        __syncthreads();
    }
    float n = f[0];
    #pragma unroll
    for (int q = 0; q < 4; ++q) {
        int k = threadIdx.x * 4 + q;
        cs_out[k] = (pre4[q] + EPSILON) / (n + KCODES * EPSILON) * n;
    }
}

// ------- fin: new_ema_w & new_embedding (+ loss finalize) -------
__global__ __launch_bounds__(256) void fin_kernel(
        const float* __restrict__ ema_w, const float* __restrict__ cs,
        float* __restrict__ emaw_inout /* holds dw */, float* __restrict__ emb_out,
        float* __restrict__ loss_inout) {
    const int i = blockIdx.x * 256 + threadIdx.x;   // f4 index, 65536 total
    const int k = i >> 6;
    float4 d = ((const float4*)emaw_inout)[i];
    float4 w = ((const float4*)ema_w)[i];
    float4 nw;
    nw.x = w.x * DECAY + (1.0f - DECAY) * d.x;
    nw.y = w.y * DECAY + (1.0f - DECAY) * d.y;
    nw.z = w.z * DECAY + (1.0f - DECAY) * d.z;
    nw.w = w.w * DECAY + (1.0f - DECAY) * d.w;
    ((float4*)emaw_inout)[i] = nw;
    float inv = 1.0f / cs[k];
    float4 e; e.x = nw.x * inv; e.y = nw.y * inv; e.z = nw.z * inv; e.w = nw.w * inv;
    ((float4*)emb_out)[i] = e;
    if (i == 0)
        loss_inout[0] = COMMITMENT_COST * loss_inout[0] / (float)((size_t)NTOK * DIM);
}

extern "C" void kernel_launch(void* const* d_in, const int* in_sizes, int n_in,
                              void* d_out, int out_size, void* d_ws, size_t ws_size,
                              hipStream_t stream) {
    const float* z      = (const float*)d_in[0];
    const float* E      = (const float*)d_in[1];
    const float* ema_cs = (const float*)d_in[2];
    const float* ema_w  = (const float*)d_in[3];
    float* out = (float*)d_out;

    float* emb = out + O_EMB;
    unsigned long long* packed = (unsigned long long*)(emb + SE_PACKED);
    float* esq  = emb + SE_ESQ;
    float* zsq  = emb + SE_ZSQ;
    int*   hist = (int*)(emb + SE_HIST);
    int*   npairs = (int*)(emb + SE_NP);
    int*   novf   = (int*)(emb + SE_NOVF);
    int*   ovf    = (int*)(emb + SE_OVF);

    unsigned short* zh = (unsigned short*)(out + SQ_ZH);
    unsigned short* eh = (unsigned short*)(out + SQ_EH);
    unsigned long long* Mg = (unsigned long long*)(out + SQ_MG);
    int* ccount = (int*)(out + SQ_CC);
    unsigned long long* cand = (unsigned long long*)(out + SQ_CAND);
    unsigned int* pairs = (unsigned int*)(out + SQ_PAIRS);

    pre_kernel<<<NTOK / 4 + KCODES / 4, 256, 0, stream>>>(
        z, E, zsq, esq, out + O_EMAW, hist, packed, out + O_LOSS,
        zh, eh, Mg, ccount, npairs, novf);
    dist_mfma_kernel<<<(NTOK / 128) * 8, 256, 0, stream>>>(
        zh, eh, esq, Mg, ccount, cand);
    recheck_a_kernel<<<NTOK / 256, 256, 0, stream>>>(
        Mg, ccount, cand, packed, pairs, npairs, ovf, novf, z, E, zsq, esq);
    recheck_b_kernel<<<256, 256, 0, stream>>>(
        z, E, zsq, esq, pairs, npairs, ovf, novf, packed);
    mid_kernel<<<NTOK / 4, 256, 0, stream>>>(z, E, packed, out + O_IDX, hist,
                                             out + O_EMAW, out + O_QUANT,
                                             out + O_LOSS);
    cs_kernel<<<1, 256, 0, stream>>>(hist, ema_cs, out + O_CS);
    fin_kernel<<<256, 256, 0, stream>>>(ema_w, out + O_CS, out + O_EMAW, emb,
                                        out + O_LOSS);
}

// Round 4
// 496.381 us; speedup vs baseline: 8.9089x; 1.0568x over previous
//
#include <hip/hip_runtime.h>
#include <math.h>

#define COMMITMENT_COST 0.25f
#define DECAY 0.99f
#define EPSILON 1e-05f
#define KCODES 1024
#define DIM 256
#define NTOK 32768

// out-buffer float offsets (concatenated return tuple)
#define O_QUANT 0
#define O_LOSS  8388608
#define O_IDX   8388609
#define O_CS    8421377
#define O_EMAW  8422401
#define O_EMB   8684545

// scratch in the new_embedding slot (262144 floats, written LAST by fin2).
// O_EMB is odd -> +1 float makes packed u64 8-byte aligned.
#define SE_PACKED 1        // u64 x 32768 -> floats [1, 65537)
#define SE_ESQ    65544
#define SE_ZSQ    66568    // 32768 floats
#define SE_HIST   99336    // 1024 ints
#define SE_NP     100360   // 1 int: pair count
#define SE_NOVF   100361   // 1 int: overflow-token count
#define SE_OVF    100362   // 32768 ints -> ends 133130
#define SE_OFFS   133136   // 1025 ints
#define SE_CUR    134168   // 1024 ints
#define SE_TLIST  135200   // 32768 ints -> ends 167968 < 262144

// scratch in the O_QUANT slot (8388608 floats, written by mid AFTER recheck).
// All consumers (dist_mfma, recheck_a/b) run before mid.
#define SQ_ZH    0         // ushort[32768*256] -> floats [0, 4194304)
#define SQ_EH    4194304   // ushort[1024*256]  -> floats [4194304, 4325376)
#define SQ_MG    4325376   // u64[32768]        -> floats [4325376, 4390912)
#define SQ_CC    4390912   // int[32768]        -> floats [4390912, 4423680)
#define SQ_CAND  4423680   // u64[56][32768] TRANSPOSED -> floats [4423680, 8093696)
#define SQ_PAIRS 8093696   // u32[262144]       -> floats [8093696, 8355840)

// exact-argmin recovery thresholds (round-1/2/3 validated: zero flips).
#define THETA 0.012f
#define THETA_F 0.008f
#define CAND_CAP 56
#define PAIR_CAP 262144

typedef __attribute__((ext_vector_type(8))) short bf16x8;
typedef __attribute__((ext_vector_type(4))) float f32x4;

__device__ __forceinline__ unsigned short f2bf(float x) {
    unsigned u = __float_as_uint(x);
    return (unsigned short)((u + 0x7FFFu + ((u >> 16) & 1u)) >> 16);  // RNE
}
__device__ __forceinline__ unsigned mono(float f) {   // order-preserving f32->u32
    unsigned u = __float_as_uint(f);
    return u ^ ((u & 0x80000000u) ? 0xFFFFFFFFu : 0x80000000u);
}
__device__ __forceinline__ float invmono(unsigned m) {
    unsigned u = m ^ ((m & 0x80000000u) ? 0x80000000u : 0xFFFFFFFFu);
    return __uint_as_float(u);
}

// exact fp32 distance, bit-identical to the passing rounds' recheck order:
// seq fmaf q=0..63 (x,y,z,w), S = An + esq, dv = S - 2*acc. Positive ->
// float-bit order works; packed (dv<<32)|idx atomicMin = first-index ties.
__device__ __forceinline__ void exact_min_update(
        const float* __restrict__ z, const float* __restrict__ E,
        const float* __restrict__ zsq, const float* __restrict__ esq,
        int token, int code, unsigned long long* __restrict__ packed) {
    const float4* zp = (const float4*)(z + (size_t)token * DIM);
    const float4* ep = (const float4*)(E + (size_t)code * DIM);
    float acc = 0.0f;
    #pragma unroll 8
    for (int q = 0; q < 64; ++q) {
        float4 a = zp[q], b = ep[q];
        acc = fmaf(a.x, b.x, acc); acc = fmaf(a.y, b.y, acc);
        acc = fmaf(a.z, b.z, acc); acc = fmaf(a.w, b.w, acc);
    }
    float S = zsq[token] + esq[code];
    float dv = S - 2.0f * acc;
    atomicMin(&packed[token],
        (((unsigned long long)__float_as_uint(dv)) << 32) | (unsigned)code);
}

// ------- pre: zsq/esq, bf16 casts zh/eh, zero hist/loss/counters, init -------
__global__ void pre_kernel(const float* __restrict__ z, const float* __restrict__ E,
                           float* __restrict__ zsq, float* __restrict__ esq,
                           int* __restrict__ hist,
                           unsigned long long* __restrict__ packed,
                           float* __restrict__ loss,
                           unsigned short* __restrict__ zh,
                           unsigned short* __restrict__ eh,
                           unsigned long long* __restrict__ Mg,
                           int* __restrict__ ccount,
                           int* __restrict__ npairs, int* __restrict__ novf) {
    const int b = blockIdx.x;
    const int wave = threadIdx.x >> 6;
    const int lane = threadIdx.x & 63;
    if (b < NTOK / 4) {
        int token = b * 4 + wave;
        float4 v = ((const float4*)(z + (size_t)token * DIM))[lane];
        ushort4 h;
        h.x = f2bf(v.x); h.y = f2bf(v.y); h.z = f2bf(v.z); h.w = f2bf(v.w);
        *(ushort4*)(zh + (size_t)token * DIM + lane * 4) = h;
        float s = v.x * v.x + v.y * v.y + v.z * v.z + v.w * v.w;
        #pragma unroll
        for (int off = 32; off > 0; off >>= 1) s += __shfl_down(s, off);
        if (lane == 0) zsq[token] = s;
        if (threadIdx.x < 4) {
            packed[b * 4 + threadIdx.x] = ~0ull;
            Mg[b * 4 + threadIdx.x] = ~0ull;
            ccount[b * 4 + threadIdx.x] = 0;
        }
        if (b == 0 && threadIdx.x == 4) loss[0] = 0.0f;
        if (b == 0 && threadIdx.x == 5) { *npairs = 0; *novf = 0; }
    } else {
        int eb = b - NTOK / 4;                 // 0..255
        int k = eb * 4 + wave;
        float4 v = ((const float4*)(E + (size_t)k * DIM))[lane];
        ushort4 h;
        h.x = f2bf(v.x); h.y = f2bf(v.y); h.z = f2bf(v.z); h.w = f2bf(v.w);
        *(ushort4*)(eh + (size_t)k * DIM + lane * 4) = h;
        float s = v.x * v.x + v.y * v.y + v.z * v.z + v.w * v.w;
        #pragma unroll
        for (int off = 32; off > 0; off >>= 1) s += __shfl_down(s, off);
        if (lane == 0) esq[k] = s;
        if (threadIdx.x < 4) hist[eb * 4 + threadIdx.x] = 0;
    }
}

// ---------------- bf16 MFMA approximate-distance pass ----------------
// delta~(t,j) = esq[j] - 2 * (zh . eh)  via mfma_f32_16x16x32_bf16.
// Tile 128 tok x 128 codes, BK=32, 4 waves (2x2), 4x4 16x16 frags/wave.
// Grid remap: toktile = bid & 255, chunk = bid >> 8 -> the 8 code-chunks of
// a token run in DIFFERENT dispatch waves; early chunks seed Mg so late
// chunks emit against the global min. cand layout TRANSPOSED [slot][NTOK]
// so recheck_a's per-token scan is coalesced.
__global__ __launch_bounds__(256) void dist_mfma_kernel(
        const unsigned short* __restrict__ zh, const unsigned short* __restrict__ eh,
        const float* __restrict__ esq,
        unsigned long long* __restrict__ Mg, int* __restrict__ ccount,
        unsigned long long* __restrict__ cand) {
    __shared__ unsigned short Als[128 * 40];
    __shared__ unsigned short Bls[128 * 40];
    __shared__ unsigned long long scr[128][2];

    const int tid = threadIdx.x;
    const int wid = tid >> 6;
    const int lane = tid & 63;
    const int wm = wid >> 1, wn = wid & 1;
    const int l15 = lane & 15, l4 = lane >> 4;
    const int tok0 = (blockIdx.x & 255) * 128;
    const int c0 = (blockIdx.x >> 8) * 128;

    // staging: thread covers rows srow, srow+64 at element col gc8..gc8+7
    const int srow = tid >> 2;              // 0..63
    const int gc8 = (tid & 3) * 8;
    const unsigned short* zsrc = zh + (size_t)(tok0 + srow) * 256 + gc8;
    const unsigned short* esrc = eh + (size_t)(c0 + srow) * 256 + gc8;
    unsigned short* adst = Als + srow * 40 + gc8;
    unsigned short* bdst = Bls + srow * 40 + gc8;

    f32x4 acc[4][4];
    #pragma unroll
    for (int i = 0; i < 4; ++i)
        #pragma unroll
        for (int j = 0; j < 4; ++j)
            acc[i][j] = (f32x4){0.f, 0.f, 0.f, 0.f};

    for (int kt = 0; kt < 8; ++kt) {
        const int kk = kt * 32;
        // issue global loads BEFORE the barrier: latency hides under the wait
        bf16x8 a0 = *(const bf16x8*)(zsrc + kk);
        bf16x8 a1 = *(const bf16x8*)(zsrc + 64 * 256 + kk);
        bf16x8 b0 = *(const bf16x8*)(esrc + kk);
        bf16x8 b1 = *(const bf16x8*)(esrc + 64 * 256 + kk);
        __syncthreads();                    // previous iter's frag reads done
        *(bf16x8*)adst = a0;
        *(bf16x8*)(adst + 64 * 40) = a1;
        *(bf16x8*)bdst = b0;
        *(bf16x8*)(bdst + 64 * 40) = b1;
        __syncthreads();
        // fragments: A row = lane&15, k = (lane>>4)*8 + i (contiguous 8 bf16);
        // B symmetric (col = lane&15). C/D: col=lane&15, row=(lane>>4)*4+reg.
        bf16x8 av[4], bv[4];
        #pragma unroll
        for (int f = 0; f < 4; ++f) {
            av[f] = *(const bf16x8*)(Als + (wm * 64 + f * 16 + l15) * 40 + l4 * 8);
            bv[f] = *(const bf16x8*)(Bls + (wn * 64 + f * 16 + l15) * 40 + l4 * 8);
        }
        #pragma unroll
        for (int i = 0; i < 4; ++i)
            #pragma unroll
            for (int j = 0; j < 4; ++j)
                acc[i][j] = __builtin_amdgcn_mfma_f32_16x16x32_bf16(
                    av[i], bv[j], acc[i][j], 0, 0, 0);
    }

    // epilogue: delta~ = sq[j] - 2*acc; per-row min; share via Mg; window emit
    float sq[4];
    #pragma unroll
    for (int j = 0; j < 4; ++j) sq[j] = esq[c0 + wn * 64 + j * 16 + l15];

    #pragma unroll
    for (int i = 0; i < 4; ++i) {
        #pragma unroll
        for (int r = 0; r < 4; ++r) {
            float v = 3.4e38f;
            #pragma unroll
            for (int j = 0; j < 4; ++j)
                v = fminf(v, sq[j] - 2.0f * acc[i][j][r]);
            #pragma unroll
            for (int m = 1; m < 16; m <<= 1)
                v = fminf(v, __shfl_xor(v, m));
            if (l15 == 0)
                scr[wm * 64 + i * 16 + l4 * 4 + r][wn] =
                    ((unsigned long long)mono(v)) << 32;
        }
    }
    __syncthreads();
    if (tid < 128) {
        unsigned long long a = scr[tid][0], b = scr[tid][1];
        unsigned long long mn = a < b ? a : b;
        unsigned long long old = atomicMin(&Mg[tok0 + tid], mn);
        scr[tid][0] = old < mn ? old : mn;   // best globally-known min
    }
    __syncthreads();
    #pragma unroll
    for (int i = 0; i < 4; ++i) {
        #pragma unroll
        for (int r = 0; r < 4; ++r) {
            const int rowl = wm * 64 + i * 16 + l4 * 4 + r;
            const float thr = invmono((unsigned)(scr[rowl][0] >> 32)) + THETA;
            #pragma unroll
            for (int j = 0; j < 4; ++j) {
                float d = sq[j] - 2.0f * acc[i][j][r];
                if (d <= thr) {
                    int token = tok0 + rowl;
                    int slot = atomicAdd(&ccount[token], 1);
                    if (slot < CAND_CAP)
                        cand[(size_t)slot * NTOK + token] =
                            (((unsigned long long)__float_as_uint(d)) << 32) |
                            (unsigned)(c0 + wn * 64 + j * 16 + l15);
                }
            }
        }
    }
}

// ------- recheck_a: per-TOKEN filter; 1 survivor -> direct write; ----------
// >=2 -> emit pairs (block-aggregated reservation). Overflow -> ovf list.
__global__ __launch_bounds__(256) void recheck_a_kernel(
        const unsigned long long* __restrict__ Mg, const int* __restrict__ ccount,
        const unsigned long long* __restrict__ cand,
        unsigned long long* __restrict__ packed,
        unsigned int* __restrict__ pairs, int* __restrict__ npairs,
        int* __restrict__ ovf, int* __restrict__ novf,
        const float* __restrict__ z, const float* __restrict__ E,
        const float* __restrict__ zsq, const float* __restrict__ esq) {
    __shared__ int ps[256];
    __shared__ int base_s;
    const int tid = threadIdx.x;
    const int token = blockIdx.x * 256 + tid;
    const int cnt = ccount[token];
    const float thr = invmono((unsigned)(Mg[token] >> 32)) + THETA_F;

    int nsurv = 0;
    int firstcode = 0;
    if (cnt > CAND_CAP) {
        int s = atomicAdd(novf, 1);
        ovf[s] = token;
    } else {
        for (int s = 0; s < cnt; ++s) {
            unsigned long long e = cand[(size_t)s * NTOK + token];
            float dt = __uint_as_float((unsigned)(e >> 32));
            if (dt <= thr) {
                ++nsurv;
                if (nsurv == 1) firstcode = (int)(unsigned)(e & 0xFFFFFFFFull);
            }
        }
    }
    const int want = (cnt <= CAND_CAP && nsurv >= 2) ? nsurv : 0;

    // block inclusive prefix-sum of want -> one atomicAdd per block
    ps[tid] = want;
    __syncthreads();
    #pragma unroll
    for (int off = 1; off < 256; off <<= 1) {
        int v = (tid >= off) ? ps[tid - off] : 0;
        __syncthreads();
        ps[tid] += v;
        __syncthreads();
    }
    if (tid == 255) base_s = atomicAdd(npairs, ps[255]);
    __syncthreads();
    const int base = base_s + ps[tid] - want;

    if (cnt <= CAND_CAP) {
        if (nsurv == 1) {
            packed[token] = (unsigned long long)(unsigned)firstcode;  // low32=idx
        } else if (nsurv >= 2) {
            if (base + nsurv <= PAIR_CAP) {
                int w = 0;
                for (int s = 0; s < cnt; ++s) {
                    unsigned long long e = cand[(size_t)s * NTOK + token];
                    float dt = __uint_as_float((unsigned)(e >> 32));
                    if (dt <= thr)
                        pairs[base + (w++)] =
                            ((unsigned)token << 10) |
                            (unsigned)(e & 0x3FFull);
                }
            } else {
                // pair-list overflow (expected never): sentinel the reserved
                // in-range slots, process survivors inline (exact, correct).
                for (int i = base; i < PAIR_CAP && i < base + nsurv; ++i)
                    pairs[i] = 0xFFFFFFFFu;
                for (int s = 0; s < cnt; ++s) {
                    unsigned long long e = cand[(size_t)s * NTOK + token];
                    float dt = __uint_as_float((unsigned)(e >> 32));
                    if (dt <= thr)
                        exact_min_update(z, E, zsq, esq, token,
                                         (int)(unsigned)(e & 0x3FFull), packed);
                }
            }
        }
    }
}

// ------- recheck_b: one LANE per (token,code) pair: exact ref-order dot ----
// Blocks [0,224): grid-stride pairs. Blocks [224,256): wave-per-overflow-token
// full 1024-code exact scan (expected 0 -> instant exit).
__global__ __launch_bounds__(256) void recheck_b_kernel(
        const float* __restrict__ z, const float* __restrict__ E,
        const float* __restrict__ zsq, const float* __restrict__ esq,
        const unsigned int* __restrict__ pairs, const int* __restrict__ npairs,
        const int* __restrict__ ovf, const int* __restrict__ novf,
        unsigned long long* __restrict__ packed) {
    if (blockIdx.x < 224) {
        int n = *npairs;
        if (n > PAIR_CAP) n = PAIR_CAP;
        for (int i = blockIdx.x * 256 + threadIdx.x; i < n; i += 224 * 256) {
            unsigned p = pairs[i];
            if (p == 0xFFFFFFFFu) continue;
            exact_min_update(z, E, zsq, esq, (int)(p >> 10), (int)(p & 1023u),
                             packed);
        }
    } else {
        const int n = *novf;
        const int lane = threadIdx.x & 63;
        int w = (blockIdx.x - 224) * 4 + (threadIdx.x >> 6);
        for (; w < n; w += 32 * 4) {
            const int token = ovf[w];
            const float An = zsq[token];
            const float4* zp = (const float4*)(z + (size_t)token * DIM);
            float best = 3.4e38f; int bid = 0x7fffffff;
            for (int code = lane; code < KCODES; code += 64) {
                const float4* ep = (const float4*)(E + (size_t)code * DIM);
                float acc = 0.0f;
                for (int q = 0; q < 64; ++q) {
                    float4 a = zp[q], b = ep[q];
                    acc = fmaf(a.x, b.x, acc); acc = fmaf(a.y, b.y, acc);
                    acc = fmaf(a.z, b.z, acc); acc = fmaf(a.w, b.w, acc);
                }
                float dv = (An + esq[code]) - 2.0f * acc;
                if (dv < best || (dv == best && code < bid)) { best = dv; bid = code; }
            }
            #pragma unroll
            for (int m = 1; m < 64; m <<= 1) {
                float ov = __shfl_xor(best, m); int oi = __shfl_xor(bid, m);
                if (ov < best || (ov == best && oi < bid)) { best = ov; bid = oi; }
            }
            if (lane == 0)
                atomicMin(&packed[token],
                    (((unsigned long long)__float_as_uint(best)) << 32) |
                    (unsigned)bid);
        }
    }
}

// ------- mid: unpack idx, hist, quant gather, loss (NO dw atomics) -------
// dw now computed by fin_gather via counting-sort buckets: removes 8.4M
// device-scope atomicAdds = 134 MB of 16B-sector HBM write-through (r3 PMC).
__global__ __launch_bounds__(256) void mid_kernel(
        const float* __restrict__ z, const float* __restrict__ E,
        const unsigned long long* __restrict__ packed,
        float* __restrict__ idx_out, int* __restrict__ hist,
        float* __restrict__ quant, float* __restrict__ loss_acc) {
    __shared__ float ls[4];
    const int wave = threadIdx.x >> 6;
    const int lane = threadIdx.x & 63;
    const int token = blockIdx.x * 4 + wave;
    const int idx = (int)(unsigned)(packed[token] & 0xFFFFFFFFull);

    if (lane == 0) {
        idx_out[token] = (float)idx;
        atomicAdd(&hist[idx], 1);
    }

    const float4 ev = *(const float4*)(E + (size_t)idx * DIM + lane * 4);
    const float4 zv = *(const float4*)(z + (size_t)token * DIM + lane * 4);
    *(float4*)(quant + (size_t)token * DIM + lane * 4) = ev;

    float dx = zv.x - ev.x, dy = zv.y - ev.y, dz = zv.z - ev.z, dww = zv.w - ev.w;
    float l = dx * dx + dy * dy + dz * dz + dww * dww;
    #pragma unroll
    for (int off = 32; off > 0; off >>= 1) l += __shfl_down(l, off);
    if (lane == 0) ls[wave] = l;
    __syncthreads();
    if (threadIdx.x == 0)
        atomicAdd(loss_acc, ls[0] + ls[1] + ls[2] + ls[3]);
}

// ------- cs: cluster-size normalize + hist prefix-sum (offs/cursor) -------
__global__ __launch_bounds__(256) void cs_kernel(
        const int* __restrict__ hist, const float* __restrict__ ema_cs,
        float* __restrict__ cs_out, int* __restrict__ offs,
        int* __restrict__ cursor) {
    __shared__ float f[256];
    __shared__ int hs[256];
    const int tid = threadIdx.x;
    float pre4[4]; int h4[4];
    float part = 0.0f; int hp = 0;
    #pragma unroll
    for (int q = 0; q < 4; ++q) {
        int k = tid * 4 + q;
        h4[q] = hist[k];
        pre4[q] = ema_cs[k] * DECAY + (1.0f - DECAY) * (float)h4[q];
        part += pre4[q];
        hp += h4[q];
    }
    f[tid] = part; hs[tid] = hp;
    __syncthreads();
    // inclusive scan of hs (Hillis-Steele)
    #pragma unroll
    for (int off = 1; off < 256; off <<= 1) {
        int v = (tid >= off) ? hs[tid - off] : 0;
        __syncthreads();
        hs[tid] += v;
        __syncthreads();
    }
    int run = hs[tid] - hp;                 // exclusive base for this thread
    #pragma unroll
    for (int q = 0; q < 4; ++q) {
        int k = tid * 4 + q;
        offs[k] = run; cursor[k] = run;
        run += h4[q];
    }
    if (tid == 255) offs[KCODES] = run;     // = NTOK
    // reduce f for n
    for (int s = 128; s > 0; s >>= 1) {
        if (tid < s) f[tid] += f[tid + s];
        __syncthreads();
    }
    float n = f[0];
    #pragma unroll
    for (int q = 0; q < 4; ++q) {
        int k = tid * 4 + q;
        cs_out[k] = (pre4[q] + EPSILON) / (n + KCODES * EPSILON) * n;
    }
}

// ------- scatter: counting-sort tokens into per-code buckets -------
__global__ __launch_bounds__(256) void scatter_kernel(
        const unsigned long long* __restrict__ packed,
        int* __restrict__ cursor, int* __restrict__ tlist) {
    const int t = blockIdx.x * 256 + threadIdx.x;
    const int idx = (int)(unsigned)(packed[t] & 0x3FFull);
    const int pos = atomicAdd(&cursor[idx], 1);
    tlist[pos] = t;
}

// ------- fin_gather: dw[k] = sum of z rows assigned to code k -------
// One block per code; 4 wave-groups stride the token list; LDS-reduce;
// single coalesced dw-row write. Replaces all dw atomics.
__global__ __launch_bounds__(256) void fin_gather_kernel(
        const float* __restrict__ z, const int* __restrict__ offs,
        const int* __restrict__ tlist, float* __restrict__ dw) {
    __shared__ float4 red[4][64];
    const int k = blockIdx.x;
    const int grp = threadIdx.x >> 6;
    const int lane = threadIdx.x & 63;
    const int s = offs[k], e = offs[k + 1];
    float4 acc = {0.f, 0.f, 0.f, 0.f};
    for (int i = s + grp; i < e; i += 4) {
        const int t = tlist[i];
        const float4 v = *(const float4*)(z + (size_t)t * DIM + lane * 4);
        acc.x += v.x; acc.y += v.y; acc.z += v.z; acc.w += v.w;
    }
    red[grp][lane] = acc;
    __syncthreads();
    if (grp == 0) {
        float4 a = red[0][lane], b = red[1][lane];
        float4 c = red[2][lane], d = red[3][lane];
        float4 o;
        o.x = (a.x + b.x) + (c.x + d.x);
        o.y = (a.y + b.y) + (c.y + d.y);
        o.z = (a.z + b.z) + (c.z + d.z);
        o.w = (a.w + b.w) + (c.w + d.w);
        *(float4*)(dw + (size_t)k * DIM + lane * 4) = o;
    }
}

// ------- fin2: new_ema_w & new_embedding (+ loss finalize) -------
__global__ __launch_bounds__(256) void fin_kernel(
        const float* __restrict__ ema_w, const float* __restrict__ cs,
        float* __restrict__ emaw_inout /* holds dw */, float* __restrict__ emb_out,
        float* __restrict__ loss_inout) {
    const int i = blockIdx.x * 256 + threadIdx.x;   // f4 index, 65536 total
    const int k = i >> 6;
    float4 d = ((const float4*)emaw_inout)[i];
    float4 w = ((const float4*)ema_w)[i];
    float4 nw;
    nw.x = w.x * DECAY + (1.0f - DECAY) * d.x;
    nw.y = w.y * DECAY + (1.0f - DECAY) * d.y;
    nw.z = w.z * DECAY + (1.0f - DECAY) * d.z;
    nw.w = w.w * DECAY + (1.0f - DECAY) * d.w;
    ((float4*)emaw_inout)[i] = nw;
    float inv = 1.0f / cs[k];
    float4 e; e.x = nw.x * inv; e.y = nw.y * inv; e.z = nw.z * inv; e.w = nw.w * inv;
    ((float4*)emb_out)[i] = e;
    if (i == 0)
        loss_inout[0] = COMMITMENT_COST * loss_inout[0] / (float)((size_t)NTOK * DIM);
}

extern "C" void kernel_launch(void* const* d_in, const int* in_sizes, int n_in,
                              void* d_out, int out_size, void* d_ws, size_t ws_size,
                              hipStream_t stream) {
    const float* z      = (const float*)d_in[0];
    const float* E      = (const float*)d_in[1];
    const float* ema_cs = (const float*)d_in[2];
    const float* ema_w  = (const float*)d_in[3];
    float* out = (float*)d_out;

    float* emb = out + O_EMB;
    unsigned long long* packed = (unsigned long long*)(emb + SE_PACKED);
    float* esq  = emb + SE_ESQ;
    float* zsq  = emb + SE_ZSQ;
    int*   hist = (int*)(emb + SE_HIST);
    int*   npairs = (int*)(emb + SE_NP);
    int*   novf   = (int*)(emb + SE_NOVF);
    int*   ovf    = (int*)(emb + SE_OVF);
    int*   offs   = (int*)(emb + SE_OFFS);
    int*   cursor = (int*)(emb + SE_CUR);
    int*   tlist  = (int*)(emb + SE_TLIST);

    unsigned short* zh = (unsigned short*)(out + SQ_ZH);
    unsigned short* eh = (unsigned short*)(out + SQ_EH);
    unsigned long long* Mg = (unsigned long long*)(out + SQ_MG);
    int* ccount = (int*)(out + SQ_CC);
    unsigned long long* cand = (unsigned long long*)(out + SQ_CAND);
    unsigned int* pairs = (unsigned int*)(out + SQ_PAIRS);

    pre_kernel<<<NTOK / 4 + KCODES / 4, 256, 0, stream>>>(
        z, E, zsq, esq, hist, packed, out + O_LOSS,
        zh, eh, Mg, ccount, npairs, novf);
    dist_mfma_kernel<<<(NTOK / 128) * 8, 256, 0, stream>>>(
        zh, eh, esq, Mg, ccount, cand);
    recheck_a_kernel<<<NTOK / 256, 256, 0, stream>>>(
        Mg, ccount, cand, packed, pairs, npairs, ovf, novf, z, E, zsq, esq);
    recheck_b_kernel<<<256, 256, 0, stream>>>(
        z, E, zsq, esq, pairs, npairs, ovf, novf, packed);
    mid_kernel<<<NTOK / 4, 256, 0, stream>>>(z, E, packed, out + O_IDX, hist,
                                             out + O_QUANT, out + O_LOSS);
    cs_kernel<<<1, 256, 0, stream>>>(hist, ema_cs, out + O_CS, offs, cursor);
    scatter_kernel<<<NTOK / 256, 256, 0, stream>>>(packed, cursor, tlist);
    fin_gather_kernel<<<KCODES, 256, 0, stream>>>(z, offs, tlist, out + O_EMAW);
    fin_kernel<<<256, 256, 0, stream>>>(ema_w, out + O_CS, out + O_EMAW, emb,
                                        out + O_LOSS);
}

// Round 6
// 491.693 us; speedup vs baseline: 8.9939x; 1.0095x over previous
//
#include <hip/hip_runtime.h>
#include <math.h>

#define COMMITMENT_COST 0.25f
#define DECAY 0.99f
#define EPSILON 1e-05f
#define KCODES 1024
#define DIM 256
#define NTOK 32768

// out-buffer float offsets (concatenated return tuple)
#define O_QUANT 0
#define O_LOSS  8388608
#define O_IDX   8388609
#define O_CS    8421377
#define O_EMAW  8422401
#define O_EMB   8684545

// scratch in the new_embedding slot (262144 floats, written LAST by fin2).
// O_EMB is odd -> +1 float makes packed u64 8-byte aligned.
#define SE_PACKED 1        // u64 x 32768 -> floats [1, 65537)
#define SE_ESQ    65544
#define SE_ZSQ    66568    // 32768 floats
#define SE_HIST   99336    // 1024 ints
#define SE_NP     100360   // 1 int: pair count
#define SE_NOVF   100361   // 1 int: overflow-token count
#define SE_OVF    100362   // 32768 ints -> ends 133130
#define SE_OFFS   133136   // 1025 ints
#define SE_CUR    134168   // 1024 ints
#define SE_TLIST  135200   // 32768 ints -> ends 167968 < 262144

// scratch in the O_QUANT slot (8388608 floats, written by mid AFTER recheck).
// All consumers (dist_mfma, recheck_a/b) run before mid.
#define SQ_ZH    0         // ushort[32768*256] -> floats [0, 4194304)
#define SQ_EH    4194304   // ushort[1024*256]  -> floats [4194304, 4325376)
#define SQ_MG    4325376   // u64[32768]        -> floats [4325376, 4390912)
#define SQ_CC    4390912   // int[32768]        -> floats [4390912, 4423680)
#define SQ_CAND  4423680   // u64[56][32768] TRANSPOSED -> floats [4423680, 8093696)
#define SQ_PAIRS 8093696   // u32[262144]       -> floats [8093696, 8355840)

// exact-argmin recovery thresholds (rounds 1-4 validated: zero flips).
// Running-min emission: emit d <= runmin_after_chunk + THETA. Superset proof:
// every true survivor has d <= truemin + THETA_F < runmin + THETA since
// runmin >= truemin always and THETA_F < THETA.
#define THETA 0.012f
#define THETA_F 0.008f
#define CAND_CAP 56
#define PAIR_CAP 262144

typedef __attribute__((ext_vector_type(8))) short bf16x8;
typedef __attribute__((ext_vector_type(4))) float f32x4;

__device__ __forceinline__ unsigned short f2bf(float x) {
    unsigned u = __float_as_uint(x);
    return (unsigned short)((u + 0x7FFFu + ((u >> 16) & 1u)) >> 16);  // RNE
}
__device__ __forceinline__ unsigned mono(float f) {   // order-preserving f32->u32
    unsigned u = __float_as_uint(f);
    return u ^ ((u & 0x80000000u) ? 0xFFFFFFFFu : 0x80000000u);
}
__device__ __forceinline__ float invmono(unsigned m) {
    unsigned u = m ^ ((m & 0x80000000u) ? 0x80000000u : 0xFFFFFFFFu);
    return __uint_as_float(u);
}

// exact fp32 distance, bit-identical to the passing rounds' recheck order:
// seq fmaf q=0..63 (x,y,z,w), S = An + esq, dv = S - 2*acc. Positive ->
// float-bit order works; packed (dv_bits<<32)|idx atomicMin = first-index ties.
__device__ __forceinline__ void exact_min_update(
        const float* __restrict__ z, const float* __restrict__ E,
        const float* __restrict__ zsq, const float* __restrict__ esq,
        int token, int code, unsigned long long* __restrict__ packed) {
    const float4* zp = (const float4*)(z + (size_t)token * DIM);
    const float4* ep = (const float4*)(E + (size_t)code * DIM);
    float acc = 0.0f;
    #pragma unroll 8
    for (int q = 0; q < 64; ++q) {
        float4 a = zp[q], b = ep[q];
        acc = fmaf(a.x, b.x, acc); acc = fmaf(a.y, b.y, acc);
        acc = fmaf(a.z, b.z, acc); acc = fmaf(a.w, b.w, acc);
    }
    float S = zsq[token] + esq[code];
    float dv = S - 2.0f * acc;
    atomicMin(&packed[token],
        (((unsigned long long)__float_as_uint(dv)) << 32) | (unsigned)code);
}

// ------- pre: zsq/esq, bf16 casts zh/eh, zero hist/loss/counters, init -------
__global__ void pre_kernel(const float* __restrict__ z, const float* __restrict__ E,
                           float* __restrict__ zsq, float* __restrict__ esq,
                           int* __restrict__ hist,
                           unsigned long long* __restrict__ packed,
                           float* __restrict__ loss,
                           unsigned short* __restrict__ zh,
                           unsigned short* __restrict__ eh,
                           int* __restrict__ npairs, int* __restrict__ novf) {
    const int b = blockIdx.x;
    const int wave = threadIdx.x >> 6;
    const int lane = threadIdx.x & 63;
    if (b < NTOK / 4) {
        int token = b * 4 + wave;
        float4 v = ((const float4*)(z + (size_t)token * DIM))[lane];
        ushort4 h;
        h.x = f2bf(v.x); h.y = f2bf(v.y); h.z = f2bf(v.z); h.w = f2bf(v.w);
        *(ushort4*)(zh + (size_t)token * DIM + lane * 4) = h;
        float s = v.x * v.x + v.y * v.y + v.z * v.z + v.w * v.w;
        #pragma unroll
        for (int off = 32; off > 0; off >>= 1) s += __shfl_down(s, off);
        if (lane == 0) zsq[token] = s;
        if (threadIdx.x < 4) packed[b * 4 + threadIdx.x] = ~0ull;
        if (b == 0 && threadIdx.x == 4) loss[0] = 0.0f;
        if (b == 0 && threadIdx.x == 5) { *npairs = 0; *novf = 0; }
    } else {
        int eb = b - NTOK / 4;                 // 0..255
        int k = eb * 4 + wave;
        float4 v = ((const float4*)(E + (size_t)k * DIM))[lane];
        ushort4 h;
        h.x = f2bf(v.x); h.y = f2bf(v.y); h.z = f2bf(v.z); h.w = f2bf(v.w);
        *(ushort4*)(eh + (size_t)k * DIM + lane * 4) = h;
        float s = v.x * v.x + v.y * v.y + v.z * v.z + v.w * v.w;
        #pragma unroll
        for (int off = 32; off > 0; off >>= 1) s += __shfl_down(s, off);
        if (lane == 0) esq[k] = s;
        if (threadIdx.x < 4) hist[eb * 4 + threadIdx.x] = 0;
    }
}

// ---------------- bf16 MFMA approximate-distance pass (token-owner) ----------
// One block OWNS 64 tokens: loops all 8 code-chunks with a running min.
// A (64x256 zh tile) staged in LDS once; B (128x32 eh chunk) staged per kt.
// 4 waves = 4 col-quarters (wn); per wave acc[4 row-frags][2 col-frags].
// Emission: d <= runmin_after_chunk + THETA (monotone tightening; ~10-15
// emits/token vs 43 before -> overflow ~0). Mg/ccount plain stores (no
// cross-block contention). Bank-group balanced b128 LDS (rows 264/40 us).
__global__ __launch_bounds__(256) void dist_mfma_kernel(
        const unsigned short* __restrict__ zh, const unsigned short* __restrict__ eh,
        const float* __restrict__ esq,
        unsigned long long* __restrict__ Mg, int* __restrict__ ccount,
        unsigned long long* __restrict__ cand) {
    __shared__ unsigned short Als[64 * 264];   // 33792 us, row 528B (16B-mult)
    __shared__ unsigned short Bls[128 * 40];   // 10240 us
    __shared__ float scr[64][4];
    __shared__ float runmin[64];
    __shared__ int lcnt[64];

    const int tid = threadIdx.x;
    const int wn = tid >> 6;                 // wave -> 32-col quarter
    const int lane = tid & 63;
    const int l15 = lane & 15, l4 = lane >> 4;
    const int tok0 = blockIdx.x * 64;

    // stage A once: 64 rows x 256 cols = 2048 bf16x8 chunks, 8 per thread
    #pragma unroll
    for (int q = 0; q < 8; ++q) {
        int c = tid + 256 * q;               // 0..2047
        int row = c >> 5, ch = c & 31;
        *(bf16x8*)(Als + row * 264 + ch * 8) =
            *(const bf16x8*)(zh + (size_t)(tok0 + row) * 256 + ch * 8);
    }
    if (tid < 64) { runmin[tid] = 3.4e38f; lcnt[tid] = 0; }
    __syncthreads();

    const int brow0 = tid >> 2, bch = tid & 3;   // B staging coords

    for (int c0 = 0; c0 < KCODES; c0 += 128) {
        f32x4 acc[4][2];
        #pragma unroll
        for (int i = 0; i < 4; ++i)
            #pragma unroll
            for (int j = 0; j < 2; ++j)
                acc[i][j] = (f32x4){0.f, 0.f, 0.f, 0.f};

        for (int kt = 0; kt < 8; ++kt) {
            const int kk = kt * 32;
            // issue B loads before the barrier (latency hides under wait)
            bf16x8 b0 = *(const bf16x8*)(
                eh + (size_t)(c0 + brow0) * 256 + kk + bch * 8);
            bf16x8 b1 = *(const bf16x8*)(
                eh + (size_t)(c0 + brow0 + 64) * 256 + kk + bch * 8);
            __syncthreads();                 // prior Bls reads / emits done
            *(bf16x8*)(Bls + brow0 * 40 + bch * 8) = b0;
            *(bf16x8*)(Bls + (brow0 + 64) * 40 + bch * 8) = b1;
            __syncthreads();
            bf16x8 av[4], bv[2];
            #pragma unroll
            for (int i = 0; i < 4; ++i)
                av[i] = *(const bf16x8*)(Als + (i * 16 + l15) * 264 + kk + l4 * 8);
            #pragma unroll
            for (int j = 0; j < 2; ++j)
                bv[j] = *(const bf16x8*)(Bls + (wn * 32 + j * 16 + l15) * 40 + l4 * 8);
            #pragma unroll
            for (int i = 0; i < 4; ++i)
                #pragma unroll
                for (int j = 0; j < 2; ++j)
                    acc[i][j] = __builtin_amdgcn_mfma_f32_16x16x32_bf16(
                        av[i], bv[j], acc[i][j], 0, 0, 0);
        }

        float sq[2];
        #pragma unroll
        for (int j = 0; j < 2; ++j) sq[j] = esq[c0 + wn * 32 + j * 16 + l15];

        // per-row wave min over this chunk's 32 cols
        #pragma unroll
        for (int i = 0; i < 4; ++i) {
            #pragma unroll
            for (int r = 0; r < 4; ++r) {
                float v = fminf(sq[0] - 2.0f * acc[i][0][r],
                                sq[1] - 2.0f * acc[i][1][r]);
                #pragma unroll
                for (int m = 1; m < 16; m <<= 1)
                    v = fminf(v, __shfl_xor(v, m));
                if (l15 == 0) scr[i * 16 + l4 * 4 + r][wn] = v;
            }
        }
        __syncthreads();
        if (tid < 64) {
            float m = fminf(fminf(scr[tid][0], scr[tid][1]),
                            fminf(scr[tid][2], scr[tid][3]));
            runmin[tid] = fminf(runmin[tid], m);
        }
        __syncthreads();
        // emit vs tightened running min (superset of true survivors)
        #pragma unroll
        for (int i = 0; i < 4; ++i) {
            #pragma unroll
            for (int r = 0; r < 4; ++r) {
                const int row = i * 16 + l4 * 4 + r;
                const float thr = runmin[row] + THETA;
                #pragma unroll
                for (int j = 0; j < 2; ++j) {
                    float d = sq[j] - 2.0f * acc[i][j][r];
                    if (d <= thr) {
                        int slot = atomicAdd(&lcnt[row], 1);
                        if (slot < CAND_CAP)
                            cand[(size_t)slot * NTOK + tok0 + row] =
                                (((unsigned long long)__float_as_uint(d)) << 32) |
                                (unsigned)(c0 + wn * 32 + j * 16 + l15);
                    }
                }
            }
        }
        // next c0's staging barriers separate these runmin reads from updates
    }
    __syncthreads();    // all emits / lcnt atomics done
    if (tid < 64) {
        Mg[tok0 + tid] = ((unsigned long long)mono(runmin[tid])) << 32;
        ccount[tok0 + tid] = lcnt[tid];
    }
}

// ------- recheck_a: per-TOKEN filter; 1 survivor -> direct write; ----------
// >=2 -> emit pairs (block-aggregated reservation). Overflow -> ovf list.
__global__ __launch_bounds__(256) void recheck_a_kernel(
        const unsigned long long* __restrict__ Mg, const int* __restrict__ ccount,
        const unsigned long long* __restrict__ cand,
        unsigned long long* __restrict__ packed,
        unsigned int* __restrict__ pairs, int* __restrict__ npairs,
        int* __restrict__ ovf, int* __restrict__ novf,
        const float* __restrict__ z, const float* __restrict__ E,
        const float* __restrict__ zsq, const float* __restrict__ esq) {
    __shared__ int ps[256];
    __shared__ int base_s;
    const int tid = threadIdx.x;
    const int token = blockIdx.x * 256 + tid;
    const int cnt = ccount[token];
    const float thr = invmono((unsigned)(Mg[token] >> 32)) + THETA_F;

    int nsurv = 0;
    int firstcode = 0;
    if (cnt > CAND_CAP) {
        int s = atomicAdd(novf, 1);
        ovf[s] = token;
    } else {
        for (int s = 0; s < cnt; ++s) {
            unsigned long long e = cand[(size_t)s * NTOK + token];
            float dt = __uint_as_float((unsigned)(e >> 32));
            if (dt <= thr) {
                ++nsurv;
                if (nsurv == 1) firstcode = (int)(unsigned)(e & 0xFFFFFFFFull);
            }
        }
    }
    const int want = (cnt <= CAND_CAP && nsurv >= 2) ? nsurv : 0;

    // block inclusive prefix-sum of want -> one atomicAdd per block
    ps[tid] = want;
    __syncthreads();
    #pragma unroll
    for (int off = 1; off < 256; off <<= 1) {
        int v = (tid >= off) ? ps[tid - off] : 0;
        __syncthreads();
        ps[tid] += v;
        __syncthreads();
    }
    if (tid == 255) base_s = atomicAdd(npairs, ps[255]);
    __syncthreads();
    const int base = base_s + ps[tid] - want;

    if (cnt <= CAND_CAP) {
        if (nsurv == 1) {
            packed[token] = (unsigned long long)(unsigned)firstcode;  // low32=idx
        } else if (nsurv >= 2) {
            if (base + nsurv <= PAIR_CAP) {
                int w = 0;
                for (int s = 0; s < cnt; ++s) {
                    unsigned long long e = cand[(size_t)s * NTOK + token];
                    float dt = __uint_as_float((unsigned)(e >> 32));
                    if (dt <= thr)
                        pairs[base + (w++)] =
                            ((unsigned)token << 10) |
                            (unsigned)(e & 0x3FFull);
                }
            } else {
                // pair-list overflow (expected never): sentinel the reserved
                // in-range slots, process survivors inline (exact, correct).
                for (int i = base; i < PAIR_CAP && i < base + nsurv; ++i)
                    pairs[i] = 0xFFFFFFFFu;
                for (int s = 0; s < cnt; ++s) {
                    unsigned long long e = cand[(size_t)s * NTOK + token];
                    float dt = __uint_as_float((unsigned)(e >> 32));
                    if (dt <= thr)
                        exact_min_update(z, E, zsq, esq, token,
                                         (int)(unsigned)(e & 0x3FFull), packed);
                }
            }
        }
    }
}

// ------- recheck_b: pairs grid-stride over ALL 256 blocks; ovf scans ------
// distributed over ALL 1024 waves (r4 fix: was 32 blocks -> 2% occupancy,
// 143us tail when overflow was structural; now overflow ~0 anyway).
__global__ __launch_bounds__(256) void recheck_b_kernel(
        const float* __restrict__ z, const float* __restrict__ E,
        const float* __restrict__ zsq, const float* __restrict__ esq,
        const unsigned int* __restrict__ pairs, const int* __restrict__ npairs,
        const int* __restrict__ ovf, const int* __restrict__ novf,
        unsigned long long* __restrict__ packed) {
    int n = *npairs;
    if (n > PAIR_CAP) n = PAIR_CAP;
    for (int i = blockIdx.x * 256 + threadIdx.x; i < n; i += 256 * 256) {
        unsigned p = pairs[i];
        if (p == 0xFFFFFFFFu) continue;
        exact_min_update(z, E, zsq, esq, (int)(p >> 10), (int)(p & 1023u),
                         packed);
    }
    // overflow tokens: one wave per token, all 1024 waves participate
    const int nov = *novf;
    const int lane = threadIdx.x & 63;
    for (int w = blockIdx.x * 4 + (threadIdx.x >> 6); w < nov; w += 256 * 4) {
        const int token = ovf[w];
        const float An = zsq[token];
        const float4* zp = (const float4*)(z + (size_t)token * DIM);
        float best = 3.4e38f; int bid = 0x7fffffff;
        for (int code = lane; code < KCODES; code += 64) {
            const float4* ep = (const float4*)(E + (size_t)code * DIM);
            float acc = 0.0f;
            for (int q = 0; q < 64; ++q) {
                float4 a = zp[q], b = ep[q];
                acc = fmaf(a.x, b.x, acc); acc = fmaf(a.y, b.y, acc);
                acc = fmaf(a.z, b.z, acc); acc = fmaf(a.w, b.w, acc);
            }
            float dv = (An + esq[code]) - 2.0f * acc;
            if (dv < best || (dv == best && code < bid)) { best = dv; bid = code; }
        }
        #pragma unroll
        for (int m = 1; m < 64; m <<= 1) {
            float ov = __shfl_xor(best, m); int oi = __shfl_xor(bid, m);
            if (ov < best || (ov == best && oi < bid)) { best = ov; bid = oi; }
        }
        if (lane == 0)
            atomicMin(&packed[token],
                (((unsigned long long)__float_as_uint(best)) << 32) |
                (unsigned)bid);
    }
}

// ------- mid: unpack idx, hist, quant gather, loss (NO dw atomics) -------
__global__ __launch_bounds__(256) void mid_kernel(
        const float* __restrict__ z, const float* __restrict__ E,
        const unsigned long long* __restrict__ packed,
        float* __restrict__ idx_out, int* __restrict__ hist,
        float* __restrict__ quant, float* __restrict__ loss_acc) {
    __shared__ float ls[4];
    const int wave = threadIdx.x >> 6;
    const int lane = threadIdx.x & 63;
    const int token = blockIdx.x * 4 + wave;
    const int idx = (int)(unsigned)(packed[token] & 0xFFFFFFFFull);

    if (lane == 0) {
        idx_out[token] = (float)idx;
        atomicAdd(&hist[idx], 1);
    }

    const float4 ev = *(const float4*)(E + (size_t)idx * DIM + lane * 4);
    const float4 zv = *(const float4*)(z + (size_t)token * DIM + lane * 4);
    *(float4*)(quant + (size_t)token * DIM + lane * 4) = ev;

    float dx = zv.x - ev.x, dy = zv.y - ev.y, dz = zv.z - ev.z, dww = zv.w - ev.w;
    float l = dx * dx + dy * dy + dz * dz + dww * dww;
    #pragma unroll
    for (int off = 32; off > 0; off >>= 1) l += __shfl_down(l, off);
    if (lane == 0) ls[wave] = l;
    __syncthreads();
    if (threadIdx.x == 0)
        atomicAdd(loss_acc, ls[0] + ls[1] + ls[2] + ls[3]);
}

// ------- cs: cluster-size normalize + hist prefix-sum (offs/cursor) -------
__global__ __launch_bounds__(256) void cs_kernel(
        const int* __restrict__ hist, const float* __restrict__ ema_cs,
        float* __restrict__ cs_out, int* __restrict__ offs,
        int* __restrict__ cursor) {
    __shared__ float f[256];
    __shared__ int hs[256];
    const int tid = threadIdx.x;
    float pre4[4]; int h4[4];
    float part = 0.0f; int hp = 0;
    #pragma unroll
    for (int q = 0; q < 4; ++q) {
        int k = tid * 4 + q;
        h4[q] = hist[k];
        pre4[q] = ema_cs[k] * DECAY + (1.0f - DECAY) * (float)h4[q];
        part += pre4[q];
        hp += h4[q];
    }
    f[tid] = part; hs[tid] = hp;
    __syncthreads();
    #pragma unroll
    for (int off = 1; off < 256; off <<= 1) {
        int v = (tid >= off) ? hs[tid - off] : 0;
        __syncthreads();
        hs[tid] += v;
        __syncthreads();
    }
    int run = hs[tid] - hp;                 // exclusive base for this thread
    #pragma unroll
    for (int q = 0; q < 4; ++q) {
        int k = tid * 4 + q;
        offs[k] = run; cursor[k] = run;
        run += h4[q];
    }
    if (tid == 255) offs[KCODES] = run;     // = NTOK
    for (int s = 128; s > 0; s >>= 1) {
        if (tid < s) f[tid] += f[tid + s];
        __syncthreads();
    }
    float n = f[0];
    #pragma unroll
    for (int q = 0; q < 4; ++q) {
        int k = tid * 4 + q;
        cs_out[k] = (pre4[q] + EPSILON) / (n + KCODES * EPSILON) * n;
    }
}

// ------- scatter: counting-sort tokens into per-code buckets -------
__global__ __launch_bounds__(256) void scatter_kernel(
        const unsigned long long* __restrict__ packed,
        int* __restrict__ cursor, int* __restrict__ tlist) {
    const int t = blockIdx.x * 256 + threadIdx.x;
    const int idx = (int)(unsigned)(packed[t] & 0x3FFull);
    const int pos = atomicAdd(&cursor[idx], 1);
    tlist[pos] = t;
}

// ------- fin_gather: dw[k] = sum of z rows assigned to code k -------
__global__ __launch_bounds__(256) void fin_gather_kernel(
        const float* __restrict__ z, const int* __restrict__ offs,
        const int* __restrict__ tlist, float* __restrict__ dw) {
    __shared__ float4 red[4][64];
    const int k = blockIdx.x;
    const int grp = threadIdx.x >> 6;
    const int lane = threadIdx.x & 63;
    const int s = offs[k], e = offs[k + 1];
    float4 acc = {0.f, 0.f, 0.f, 0.f};
    for (int i = s + grp; i < e; i += 4) {
        const int t = tlist[i];
        const float4 v = *(const float4*)(z + (size_t)t * DIM + lane * 4);
        acc.x += v.x; acc.y += v.y; acc.z += v.z; acc.w += v.w;
    }
    red[grp][lane] = acc;
    __syncthreads();
    if (grp == 0) {
        float4 a = red[0][lane], b = red[1][lane];
        float4 c = red[2][lane], d = red[3][lane];
        float4 o;
        o.x = (a.x + b.x) + (c.x + d.x);
        o.y = (a.y + b.y) + (c.y + d.y);
        o.z = (a.z + b.z) + (c.z + d.z);
        o.w = (a.w + b.w) + (c.w + d.w);
        *(float4*)(dw + (size_t)k * DIM + lane * 4) = o;
    }
}

// ------- fin2: new_ema_w & new_embedding (+ loss finalize) -------
__global__ __launch_bounds__(256) void fin_kernel(
        const float* __restrict__ ema_w, const float* __restrict__ cs,
        float* __restrict__ emaw_inout /* holds dw */, float* __restrict__ emb_out,
        float* __restrict__ loss_inout) {
    const int i = blockIdx.x * 256 + threadIdx.x;   // f4 index, 65536 total
    const int k = i >> 6;
    float4 d = ((const float4*)emaw_inout)[i];
    float4 w = ((const float4*)ema_w)[i];
    float4 nw;
    nw.x = w.x * DECAY + (1.0f - DECAY) * d.x;
    nw.y = w.y * DECAY + (1.0f - DECAY) * d.y;
    nw.z = w.z * DECAY + (1.0f - DECAY) * d.z;
    nw.w = w.w * DECAY + (1.0f - DECAY) * d.w;
    ((float4*)emaw_inout)[i] = nw;
    float inv = 1.0f / cs[k];
    float4 e; e.x = nw.x * inv; e.y = nw.y * inv; e.z = nw.z * inv; e.w = nw.w * inv;
    ((float4*)emb_out)[i] = e;
    if (i == 0)
        loss_inout[0] = COMMITMENT_COST * loss_inout[0] / (float)((size_t)NTOK * DIM);
}

extern "C" void kernel_launch(void* const* d_in, const int* in_sizes, int n_in,
                              void* d_out, int out_size, void* d_ws, size_t ws_size,
                              hipStream_t stream) {
    const float* z      = (const float*)d_in[0];
    const float* E      = (const float*)d_in[1];
    const float* ema_cs = (const float*)d_in[2];
    const float* ema_w  = (const float*)d_in[3];
    float* out = (float*)d_out;

    float* emb = out + O_EMB;
    unsigned long long* packed = (unsigned long long*)(emb + SE_PACKED);
    float* esq  = emb + SE_ESQ;
    float* zsq  = emb + SE_ZSQ;
    int*   hist = (int*)(emb + SE_HIST);
    int*   npairs = (int*)(emb + SE_NP);
    int*   novf   = (int*)(emb + SE_NOVF);
    int*   ovf    = (int*)(emb + SE_OVF);
    int*   offs   = (int*)(emb + SE_OFFS);
    int*   cursor = (int*)(emb + SE_CUR);
    int*   tlist  = (int*)(emb + SE_TLIST);

    unsigned short* zh = (unsigned short*)(out + SQ_ZH);
    unsigned short* eh = (unsigned short*)(out + SQ_EH);
    unsigned long long* Mg = (unsigned long long*)(out + SQ_MG);
    int* ccount = (int*)(out + SQ_CC);
    unsigned long long* cand = (unsigned long long*)(out + SQ_CAND);
    unsigned int* pairs = (unsigned int*)(out + SQ_PAIRS);

    pre_kernel<<<NTOK / 4 + KCODES / 4, 256, 0, stream>>>(
        z, E, zsq, esq, hist, packed, out + O_LOSS, zh, eh, npairs, novf);
    dist_mfma_kernel<<<NTOK / 64, 256, 0, stream>>>(
        zh, eh, esq, Mg, ccount, cand);
    recheck_a_kernel<<<NTOK / 256, 256, 0, stream>>>(
        Mg, ccount, cand, packed, pairs, npairs, ovf, novf, z, E, zsq, esq);
    recheck_b_kernel<<<256, 256, 0, stream>>>(
        z, E, zsq, esq, pairs, npairs, ovf, novf, packed);
    mid_kernel<<<NTOK / 4, 256, 0, stream>>>(z, E, packed, out + O_IDX, hist,
                                             out + O_QUANT, out + O_LOSS);
    cs_kernel<<<1, 256, 0, stream>>>(hist, ema_cs, out + O_CS, offs, cursor);
    scatter_kernel<<<NTOK / 256, 256, 0, stream>>>(packed, cursor, tlist);
    fin_gather_kernel<<<KCODES, 256, 0, stream>>>(z, offs, tlist, out + O_EMAW);
    fin_kernel<<<256, 256, 0, stream>>>(ema_w, out + O_CS, out + O_EMAW, emb,
                                        out + O_LOSS);
}